// Round 10
// baseline (4629.162 us; speedup 1.0000x reference)
//
#include <hip/hip_runtime.h>
#include <cmath>

typedef unsigned long long u64;
typedef unsigned int u32;
typedef unsigned char u8;

#define SCAN_BLOCK 256
#define SCAN_ELEMS 8
#define SCAN_TILE (SCAN_BLOCK * SCAN_ELEMS)

// counting-sort bins: 512 vertices per bin (V=200000 -> NB=391 <= 512).
// record packing (mn&511)<<18 | mx requires V <= 2^18.
#define BIN_SHIFT 9
#define BIN_VR 512
#define TETS_PER_BLOCK 2048

// decoupled-lookback flags for the fused sort+scan+verts kernel
#define FAGG (1ull << 62)
#define FINC (2ull << 62)
#define VMASK ((1ull << 62) - 1ull)

__constant__ int d_NUMTRI[16] = {0,1,1,2,1,2,2,1,1,2,2,1,2,1,1,0};
__constant__ int d_TRI[16][6] = {
 {-1,-1,-1,-1,-1,-1},{1,0,2,-1,-1,-1},{4,0,3,-1,-1,-1},{1,4,2,1,3,4},
 {3,1,5,-1,-1,-1},{2,3,0,2,5,3},{1,4,0,1,5,4},{4,2,5,-1,-1,-1},
 {4,5,2,-1,-1,-1},{4,1,0,4,5,1},{3,2,0,3,5,2},{1,3,5,-1,-1,-1},
 {4,1,2,4,3,1},{3,0,4,-1,-1,-1},{2,0,1,-1,-1,-1},{-1,-1,-1,-1,-1,-1}};
__constant__ int d_E0[6] = {0,0,0,1,1,2};
__constant__ int d_E1[6] = {1,2,3,2,3,3};

// ---------------- exclusive scan (2-dispatch: scanA + fused scanCf) --------
// NOTE: tet m1/m2 scan MUST be u64 — running m1 total needs 19 bits packed at
// bit 21 (overflowed u32 in an early round).
template <typename T>
__global__ void scanA_t(const T* in, T* out, int n, T* blockSums) {
    __shared__ T tsum[SCAN_BLOCK];
    int tbase = blockIdx.x * SCAN_TILE + threadIdx.x * SCAN_ELEMS;
    T vals[SCAN_ELEMS];
    T run = 0;
    for (int k = 0; k < SCAN_ELEMS; ++k) {
        int i = tbase + k;
        T v = (i < n) ? in[i] : (T)0;
        vals[k] = run;
        run += v;
    }
    tsum[threadIdx.x] = run;
    __syncthreads();
    for (int off = 1; off < SCAN_BLOCK; off <<= 1) {
        T v = (threadIdx.x >= (unsigned)off) ? tsum[threadIdx.x - off] : (T)0;
        __syncthreads();
        tsum[threadIdx.x] += v;
        __syncthreads();
    }
    T texcl = (threadIdx.x == 0) ? (T)0 : tsum[threadIdx.x - 1];
    for (int k = 0; k < SCAN_ELEMS; ++k) {
        int i = tbase + k;
        if (i < n) out[i] = texcl + vals[k];
    }
    if (threadIdx.x == SCAN_BLOCK - 1) blockSums[blockIdx.x] = tsum[SCAN_BLOCK - 1];
}

// Fused scanB+scanC: every block redundantly scans the <=2048 blockSums in
// LDS and adds its exclusive prefix. Block 0 also emits the grand total.
template <typename T>
__global__ void scanCf_t(T* out, int n, const T* bs, int nb, T* totalOut) {
    __shared__ T sh[2048];
    for (int i = threadIdx.x; i < 2048; i += 256) sh[i] = (i < nb) ? bs[i] : (T)0;
    __syncthreads();
    for (int off = 1; off < 2048; off <<= 1) {
        T v[8];
        for (int k = 0; k < 8; ++k) {
            int i = threadIdx.x + k * 256;
            v[k] = (i >= off) ? sh[i - off] : (T)0;
        }
        __syncthreads();
        for (int k = 0; k < 8; ++k) sh[threadIdx.x + k * 256] += v[k];
        __syncthreads();
    }
    if (totalOut && blockIdx.x == 0 && threadIdx.x == 0)
        *totalOut = (nb > 0) ? sh[nb - 1] : (T)0;
    T add = (blockIdx.x == 0) ? (T)0 : sh[blockIdx.x - 1];
    int base = blockIdx.x * SCAN_TILE;
    int end = base + SCAN_TILE; if (end > n) end = n;
    for (int i = base + threadIdx.x; i < end; i += SCAN_BLOCK) out[i] += add;
}

// ---------------- pipeline ----------------
// Pass A: classify tets + per-block LDS histogram of crossing edges over
// bins (binned structure is load-bearing: R6's direct global scatter = 64B
// write-allocate per 8B record = 285us).
__global__ __launch_bounds__(256) void k_classify_hist(
    const int* tet, const float* sdf, u8* ti8, u64* tetPack,
    u32* blockHist, int T, int NB, int gB) {
    __shared__ u32 hist[BIN_VR];
    for (int i = threadIdx.x; i < NB; i += 256) hist[i] = 0;
    __syncthreads();
    int base = blockIdx.x * TETS_PER_BLOCK;
    for (int it = 0; it < TETS_PER_BLOCK / 256; ++it) {
        int t = base + it * 256 + threadIdx.x;
        if (t < T) {
            int4 q = reinterpret_cast<const int4*>(tet)[t];
            int ti = (sdf[q.x] > 0.0f ? 1 : 0) | (sdf[q.y] > 0.0f ? 2 : 0) |
                     (sdf[q.z] > 0.0f ? 4 : 0) | (sdf[q.w] > 0.0f ? 8 : 0);
            ti8[t] = (u8)ti;
            int nt = d_NUMTRI[ti];
            tetPack[t] = ((u64)(nt == 1 ? 1 : 0) << 21) | (u64)(nt == 2 ? 1 : 0);
            if (nt != 0) {
                int idx[4] = {q.x, q.y, q.z, q.w};
                #pragma unroll
                for (int e = 0; e < 6; ++e) {
                    int e0 = d_E0[e], e1 = d_E1[e];
                    if (((ti >> e0) ^ (ti >> e1)) & 1) {
                        int a = idx[e0], b = idx[e1];
                        int mn = a < b ? a : b;
                        atomicAdd(&hist[mn >> BIN_SHIFT], 1u);
                    }
                }
            }
        }
    }
    __syncthreads();
    for (int i = threadIdx.x; i < NB; i += 256)
        blockHist[(size_t)i * gB + blockIdx.x] = hist[i];
}

// Pass B: block-local LDS cursors hand out contiguous slots in the
// bin-sorted record array. Records carry prov = 6*t + e.
__global__ __launch_bounds__(256) void k_binfill(
    const int* tet, const u8* ti8, const u32* blockHistScan,
    u32* binData, u32* binProv, int T, int NB, int gB) {
    __shared__ u32 cur[BIN_VR];
    for (int i = threadIdx.x; i < NB; i += 256)
        cur[i] = blockHistScan[(size_t)i * gB + blockIdx.x];
    __syncthreads();
    int base = blockIdx.x * TETS_PER_BLOCK;
    for (int it = 0; it < TETS_PER_BLOCK / 256; ++it) {
        int t = base + it * 256 + threadIdx.x;
        if (t < T) {
            int ti = ti8[t];
            if (d_NUMTRI[ti] != 0) {
                int4 q = reinterpret_cast<const int4*>(tet)[t];
                int idx[4] = {q.x, q.y, q.z, q.w};
                #pragma unroll
                for (int e = 0; e < 6; ++e) {
                    int e0 = d_E0[e], e1 = d_E1[e];
                    if (((ti >> e0) ^ (ti >> e1)) & 1) {
                        int a = idx[e0], b = idx[e1];
                        int mn = a < b ? a : b;
                        int mx = a < b ? b : a;
                        u32 slot = atomicAdd(&cur[mn >> BIN_SHIFT], 1u);
                        binData[slot] = ((u32)(mn & (BIN_VR - 1)) << 18) | (u32)mx;
                        binProv[slot] = 6u * (u32)t + (u32)e;
                    }
                }
            }
        }
    }
}

// one block per bin: LDS histogram over the bin's records, then LDS scan of
// the 512 padded counts -> bucketCnt + within-bin offsets + per-bin total.
// Also zeroes the lookback state (partials + ticket) for k_sortverts.
__global__ __launch_bounds__(256) void k_bincount2(
    const u32* blockHistScan, const u32* totalPtr, const u32* binData,
    u32* bucketCnt, u32* bucketStart, u32* binTotals,
    u64* partials, u32* ticket, int NPart, int V, int NB, int gB) {
    for (int i = blockIdx.x * 256 + threadIdx.x; i < NPart; i += gridDim.x * 256)
        partials[i] = 0ull;
    if (blockIdx.x == 0 && threadIdx.x == 0) *ticket = 0u;
    int bin = blockIdx.x;
    __shared__ u32 hist[BIN_VR];
    __shared__ u32 sc[BIN_VR];
    for (int i = threadIdx.x; i < BIN_VR; i += 256) hist[i] = 0;
    __syncthreads();
    u32 s = blockHistScan[(size_t)bin * gB];
    u32 e = (bin + 1 < NB) ? blockHistScan[(size_t)(bin + 1) * gB] : *totalPtr;
    for (u32 i = s + threadIdx.x; i < e; i += 256)
        atomicAdd(&hist[binData[i] >> 18], 1u);
    __syncthreads();
    int t0 = threadIdx.x, t1 = threadIdx.x + 256;
    sc[t0] = (hist[t0] + 3u) & ~3u;          // pad4; empty buckets stay 0
    sc[t1] = (hist[t1] + 3u) & ~3u;
    __syncthreads();
    for (int off = 1; off < BIN_VR; off <<= 1) {
        u32 v0 = (t0 >= off) ? sc[t0 - off] : 0u;
        u32 v1 = (t1 >= off) ? sc[t1 - off] : 0u;
        __syncthreads();
        sc[t0] += v0; sc[t1] += v1;          // inclusive scan
        __syncthreads();
    }
    int vbase = bin << BIN_SHIFT;
    for (int i = threadIdx.x; i < BIN_VR; i += 256) {
        int v = vbase + i;
        if (v < V) {
            u32 h = hist[i];
            bucketCnt[v] = h;
            bucketStart[v] = sc[i] - ((h + 3u) & ~3u);   // local excl offset
        }
    }
    if (threadIdx.x == 0) binTotals[bin] = sc[BIN_VR - 1];
}

// one block per bin: redundant LDS scan of the <=512 bin totals -> binBase;
// finalize bucketStart (absolute), then scatter (mx,prov) uint2 records into
// the bin's L2-resident window via LDS cursors.
__global__ __launch_bounds__(256) void k_binscatter2(
    const u32* blockHistScan, const u32* totalPtr, const u32* binData,
    const u32* binProv, const u32* binTotals, u32* bucketStart, uint2* rec2,
    int V, int NB, int gB) {
    int bin = blockIdx.x;
    __shared__ u32 bt[BIN_VR];
    __shared__ u32 cur[BIN_VR];
    int t0 = threadIdx.x, t1 = threadIdx.x + 256;
    bt[t0] = (t0 < NB) ? binTotals[t0] : 0u;
    bt[t1] = (t1 < NB) ? binTotals[t1] : 0u;
    __syncthreads();
    for (int off = 1; off < BIN_VR; off <<= 1) {
        u32 v0 = (t0 >= off) ? bt[t0 - off] : 0u;
        u32 v1 = (t1 >= off) ? bt[t1 - off] : 0u;
        __syncthreads();
        bt[t0] += v0; bt[t1] += v1;
        __syncthreads();
    }
    u32 binBase = (bin == 0) ? 0u : bt[bin - 1];
    int vbase = bin << BIN_SHIFT;
    for (int i = threadIdx.x; i < BIN_VR; i += 256) {
        int v = vbase + i;
        if (v < V) {
            u32 a = binBase + bucketStart[v];
            bucketStart[v] = a;
            cur[i] = a;
        } else cur[i] = 0u;
    }
    __syncthreads();
    u32 s = blockHistScan[(size_t)bin * gB];
    u32 e = (bin + 1 < NB) ? blockHistScan[(size_t)(bin + 1) * gB] : *totalPtr;
    for (u32 i = s + threadIdx.x; i < e; i += 256) {
        u32 rec = binData[i];
        u32 pv = binProv[i];
        u32 slot = atomicAdd(&cur[rec >> 18], 1u);
        rec2[slot] = make_uint2(rec & 0x3FFFFu, pv);
    }
}

// FUSED sort+dedup + decoupled-lookback scan + vertex emission.
// Replaces k_sortdedup + k_sortbig + scan(crossCnt) + k_verts. Per block:
// 4 waves, 1 bucket each (wave-uniform n, proven-best shape). Ticket-ordered
// blocks + agent-scope atomic lookback give the global unique-prefix
// (crossScan) in-kernel; deadlock-free (blocks wait only on earlier tickets).
// R9 BUG FIXED: big-path isFirst predicate had a mangled `c < 0` term that
// disabled ALL unique flags for 64<n<=256 buckets.
__global__ __launch_bounds__(256) void k_sortverts(
    const u32* bucketCnt, const u32* bucketStart, uint2* rec2,
    u8* idxmap, u32* crossScan, u64* partials, u32* ticket, u32* NePtr,
    const float* pos, const float* sdf, float* out, int V, int NBlk)
{
    __shared__ u32 uarr[4];
    __shared__ u32 svbid;
    __shared__ u32 sExcl;
    if (threadIdx.x == 0) svbid = atomicAdd(ticket, 1u);
    __syncthreads();
    int vbid = (int)svbid;
    int wid = threadIdx.x >> 6;
    int lane = threadIdx.x & 63;
    int v = vbid * 4 + wid;

    int n = 0;
    u32 u = 0;
    long long start = 0;
    // small-path state (n<=64)
    bool nfA = false; int idxA = 0; u32 sortedA = 0;
    // big-path state (64<n<=256): kf = key | isFirst<<31 (keys < 2^18)
    u32 kfB[4]; int ulessB[4]; int chunksB = 0;

    // ---- phase 1: per-wave sort + dedup + idxmap scatter ----
    if (v < V) {
        n = (int)bucketCnt[v];
        start = (long long)bucketStart[v];
        if (n == 0) {
        } else if (n <= 64) {
            uint2 rp = (lane < n) ? rec2[start + lane] : make_uint2(0xFFFFFFFFu, 0u);
            u32 key = rp.x, prov = rp.y;
            int rank = 0;
            for (int j = 0; j < n; ++j) {       // wave-uniform bound, avg ~15
                u32 kj = (u32)__shfl((int)key, j);
                rank += (kj < key || (kj == key && j < lane)) ? 1 : 0;
            }
            u32 sorted = (u32)__builtin_amdgcn_ds_permute(rank << 2, (int)key);
            u32 prev = (u32)__shfl((int)sorted, lane - 1);
            bool nf = (lane < n) && (lane == 0 || prev != sorted);
            u64 m = __ballot(nf);
            int idx = __popcll(m & ((1ull << lane) - 1ull));
            int ldSorted = nf ? idx : idx - 1;
            int ldOrig = __shfl(ldSorted, rank);
            if (lane < n) idxmap[prov] = (u8)ldOrig;
            u = (u32)__popcll(m);
            nfA = nf; idxA = idx; sortedA = sorted;
        } else if (n <= 256) {
            int chunks = (n + 63) >> 6;         // 2..4
            u32 prov[4];
            int myi[4];
            #pragma unroll
            for (int c = 0; c < 4; ++c) {
                myi[c] = (c << 6) + lane;
                kfB[c] = 0xFFFFFFFFu; prov[c] = 0u;
                if (c < chunks && myi[c] < n) {
                    uint2 rp = rec2[start + myi[c]];
                    kfB[c] = rp.x; prov[c] = rp.y;
                }
            }
            // pass 1: does an earlier element carry my key?
            bool tie[4] = {false, false, false, false};
            #pragma unroll
            for (int c2 = 0; c2 < 4; ++c2) {
                if (c2 < chunks) {
                    int base2 = c2 << 6;
                    int lim = n - base2; if (lim > 64) lim = 64;
                    for (int j = 0; j < lim; ++j) {
                        u32 kj = (u32)__shfl((int)kfB[c2], j);
                        int jg = base2 + j;
                        #pragma unroll
                        for (int c = 0; c < 4; ++c) {
                            if (c < chunks)
                                tie[c] = tie[c] | (kj == kfB[c] && jg < myi[c]);
                        }
                    }
                }
            }
            u32 uq = 0;
            #pragma unroll
            for (int c = 0; c < 4; ++c) {
                bool isf = (c < chunks) && (myi[c] < n) && !tie[c];   // R9 fix
                kfB[c] = kfB[c] | (isf ? 0x80000000u : 0u);
                u64 bal = __ballot(isf);
                uq += (u32)__popcll(bal);
            }
            // pass 2: count distinct smaller keys (isFirst in bit31)
            int uless[4] = {0, 0, 0, 0};
            #pragma unroll
            for (int c2 = 0; c2 < 4; ++c2) {
                if (c2 < chunks) {
                    int base2 = c2 << 6;
                    int lim = n - base2; if (lim > 64) lim = 64;
                    for (int j = 0; j < lim; ++j) {
                        u32 kfj = (u32)__shfl((int)kfB[c2], j);
                        u32 kj = kfj & 0x7FFFFFFFu;
                        bool fj = (kfj & 0x80000000u) != 0u;
                        #pragma unroll
                        for (int c = 0; c < 4; ++c) {
                            if (c < chunks) {
                                u32 myk = kfB[c] & 0x7FFFFFFFu;
                                uless[c] += (fj && kj < myk) ? 1 : 0;
                            }
                        }
                    }
                }
            }
            #pragma unroll
            for (int c = 0; c < 4; ++c) {
                ulessB[c] = uless[c];
                if (c < chunks && myi[c] < n)
                    idxmap[prov[c]] = (u8)uless[c];
            }
            u = uq; chunksB = chunks;
        } else {
            // n>256: needs a vertex in ~85+ tets, P~0. Serial fallback with
            // rec2 compaction (phase 3 re-reads it).
            int uc = 0;
            if (lane == 0) {
                for (int i = 1; i < n; ++i) {
                    uint2 kk = rec2[start + i];
                    int j = i - 1;
                    while (j >= 0 && rec2[start + j].x > kk.x) {
                        rec2[start + j + 1] = rec2[start + j]; --j;
                    }
                    rec2[start + j + 1] = kk;
                }
                u32 prevk = 0xFFFFFFFFu;
                for (int i = 0; i < n; ++i) {
                    uint2 r = rec2[start + i];
                    if (r.x != prevk) { rec2[start + uc].x = r.x; ++uc; prevk = r.x; }
                    idxmap[r.y] = (u8)(uc - 1);
                }
            }
            u = (u32)__shfl(uc, 0);
        }
    }
    if (lane == 0) uarr[wid] = u;
    __syncthreads();

    // ---- phase 2: block aggregate + decoupled lookback (wave 0) ----
    if (threadIdx.x < 64) {
        u32 B = uarr[0] + uarr[1] + uarr[2] + uarr[3];
        u32 run = 0;
        if (vbid == 0) {
            if (threadIdx.x == 0)
                __hip_atomic_store(&partials[0], FINC | (u64)B,
                                   __ATOMIC_RELEASE, __HIP_MEMORY_SCOPE_AGENT);
        } else {
            if (threadIdx.x == 0)
                __hip_atomic_store(&partials[vbid], FAGG | (u64)B,
                                   __ATOMIC_RELEASE, __HIP_MEMORY_SCOPE_AGENT);
            int base = vbid;
            for (;;) {
                int i = base - 1 - (int)threadIdx.x;    // lane0 = nearest
                u64 val = 0;
                if (i >= 0) {
                    for (;;) {
                        val = __hip_atomic_load(&partials[i], __ATOMIC_ACQUIRE,
                                                __HIP_MEMORY_SCOPE_AGENT);
                        if ((val >> 62) != 0ull) break;
                        __builtin_amdgcn_s_sleep(1);
                    }
                }
                bool inc = (i >= 0) && ((val >> 62) == 2ull);
                u64 ball = __ballot(inc);
                int fl = ball ? (__ffsll((unsigned long long)ball) - 1) : 64;
                u32 c32 = (i >= 0 && (int)threadIdx.x <= fl)
                              ? (u32)(val & VMASK) : 0u;
                #pragma unroll
                for (int o = 1; o < 64; o <<= 1)
                    c32 += (u32)__shfl_xor((int)c32, o);
                run += c32;
                if (ball) break;
                base -= 64;
            }
            if (threadIdx.x == 0)
                __hip_atomic_store(&partials[vbid], FINC | (u64)(run + B),
                                   __ATOMIC_RELEASE, __HIP_MEMORY_SCOPE_AGENT);
        }
        if (threadIdx.x == 0) {
            sExcl = run;
            if (vbid == NBlk - 1) *NePtr = run + B;
        }
    }
    __syncthreads();

    // ---- phase 3: crossScan write + vertex emission from registers ----
    u32 wex = sExcl;
    if (wid > 0) wex += uarr[0];
    if (wid > 1) wex += uarr[1];
    if (wid > 2) wex += uarr[2];
    if (v < V) {
        if (lane == 0) crossScan[v] = wex;
        if (u > 0) {
            float s0 = sdf[v];
            float p0x = pos[3 * v], p0y = pos[3 * v + 1], p0z = pos[3 * v + 2];
            long long cBase = (long long)wex;
            if (n <= 64) {
                if (nfA) {
                    int b = (int)sortedA;
                    float s1 = sdf[b];
                    float d = s0 - s1;
                    float w0 = -s1 / d, w1 = s0 / d;
                    long long k = cBase + idxA;
                    out[3 * k + 0] = p0x * w0 + pos[3 * b + 0] * w1;
                    out[3 * k + 1] = p0y * w0 + pos[3 * b + 1] * w1;
                    out[3 * k + 2] = p0z * w0 + pos[3 * b + 2] * w1;
                }
            } else if (n <= 256) {
                #pragma unroll
                for (int c = 0; c < 4; ++c) {
                    if (c < chunksB) {
                        int myi = (c << 6) + lane;
                        if (myi < n && (kfB[c] & 0x80000000u)) {
                            int b = (int)(kfB[c] & 0x7FFFFFFFu);
                            float s1 = sdf[b];
                            float d = s0 - s1;
                            float w0 = -s1 / d, w1 = s0 / d;
                            long long k = cBase + ulessB[c];
                            out[3 * k + 0] = p0x * w0 + pos[3 * b + 0] * w1;
                            out[3 * k + 1] = p0y * w0 + pos[3 * b + 1] * w1;
                            out[3 * k + 2] = p0z * w0 + pos[3 * b + 2] * w1;
                        }
                    }
                }
            } else if (lane == 0) {
                for (int i = 0; i < (int)u; ++i) {
                    int b = (int)rec2[start + i].x;
                    float s1 = sdf[b];
                    float d = s0 - s1;
                    float w0 = -s1 / d, w1 = s0 / d;
                    long long k = cBase + i;
                    out[3 * k + 0] = p0x * w0 + pos[3 * b + 0] * w1;
                    out[3 * k + 1] = p0y * w0 + pos[3 * b + 1] * w1;
                    out[3 * k + 2] = p0z * w0 + pos[3 * b + 2] * w1;
                }
            }
        }
    }
}

// faces + uv_idx + fused uv grid (Ngrid^2 >= T since M == T). Edge->vertex
// id: u8 idx_map[6t+e] = local dedup index; global id = crossScan[a]+local.
__global__ void k_faces(const int* tet, const u8* ti8, const u64* tetScan,
                        const u8* idxmap, const u32* crossScan,
                        const u64* meta0, const u32* NePtr,
                        float* out, int T, int Ngrid, long long uvFloats)
{
    int t = blockIdx.x * 256 + threadIdx.x;
    int uvTotal = Ngrid * Ngrid;
    if (t >= T && t >= uvTotal) return;

    u64 tot = *meta0;
    int C1 = (int)((tot >> 21) & 0x1fffffull);
    int C2 = (int)(tot & 0x1fffffull);
    int Ne = (int)*NePtr;
    long long facesBase = 3LL * Ne;
    long long F = (long long)C1 + 2LL * C2;
    long long uvBase = facesBase + 3LL * F;
    long long uvIdxBase = uvBase + uvFloats;

    if (t < uvTotal) {          // fused uv-grid write
        int i = t / Ngrid, j = t % Ngrid;
        double step = (Ngrid > 1) ? (1.0 - 1.0 / (double)Ngrid) / (double)(Ngrid - 1) : 0.0;
        float x = (float)((double)j * step);
        float y = (float)((double)i * step);
        float pad = (float)(0.9 / (double)Ngrid);
        long long o = uvBase + 8LL * t;
        out[o + 0] = x;       out[o + 1] = y;
        out[o + 2] = x + pad; out[o + 3] = y;
        out[o + 4] = x + pad; out[o + 5] = y + pad;
        out[o + 6] = x;       out[o + 7] = y + pad;
    }
    if (t >= T) return;

    int ti = ti8[t];
    int nt = d_NUMTRI[ti];
    if (nt == 0) return;

    int4 q = reinterpret_cast<const int4*>(tet)[t];
    int idx[4] = {q.x, q.y, q.z, q.w};
    const unsigned short* imp =
        reinterpret_cast<const unsigned short*>(idxmap + 6ll * t);
    unsigned short w0 = imp[0], w1 = imp[1], w2 = imp[2];
    u32 im[6] = {(u32)(w0 & 0xFF), (u32)(w0 >> 8),
                 (u32)(w1 & 0xFF), (u32)(w1 >> 8),
                 (u32)(w2 & 0xFF), (u32)(w2 >> 8)};
    const int* row = d_TRI[ti];

    int emap[6];
    unsigned done = 0;
    float fv[6];
    #pragma unroll
    for (int j = 0; j < 6; ++j) {
        if (j >= 3 * nt) break;
        int e = row[j];
        if (!((done >> e) & 1)) {
            done |= 1u << e;
            int a = idx[d_E0[e]], b = idx[d_E1[e]];
            if (b < a) a = b;                  // a = min endpoint = bucket
            emap[e] = (int)crossScan[a] + (int)im[e];
        }
        fv[j] = (float)emap[e];
    }

    u64 sc = tetScan[t];
    int r1s = (int)((sc >> 21) & 0x1fffffull);
    int r2s = (int)(sc & 0x1fffffull);
    int tet_idx = (t / Ngrid) * Ngrid + (t % Ngrid);

    if (nt == 1) {
        long long f = r1s;
        out[facesBase + 3 * f + 0] = fv[0];
        out[facesBase + 3 * f + 1] = fv[1];
        out[facesBase + 3 * f + 2] = fv[2];
        out[uvIdxBase + 3 * f + 0] = (float)(4 * tet_idx);
        out[uvIdxBase + 3 * f + 1] = (float)(4 * tet_idx + 1);
        out[uvIdxBase + 3 * f + 2] = (float)(4 * tet_idx + 2);
    } else {
        long long f0 = (long long)C1 + 2LL * r2s;
        out[facesBase + 3 * f0 + 0] = fv[0];
        out[facesBase + 3 * f0 + 1] = fv[1];
        out[facesBase + 3 * f0 + 2] = fv[2];
        out[facesBase + 3 * (f0 + 1) + 0] = fv[3];
        out[facesBase + 3 * (f0 + 1) + 1] = fv[4];
        out[facesBase + 3 * (f0 + 1) + 2] = fv[5];
        out[uvIdxBase + 3 * f0 + 0] = (float)(4 * tet_idx);
        out[uvIdxBase + 3 * f0 + 1] = (float)(4 * tet_idx + 1);
        out[uvIdxBase + 3 * f0 + 2] = (float)(4 * tet_idx + 2);
        out[uvIdxBase + 3 * (f0 + 1) + 0] = (float)(4 * tet_idx);
        out[uvIdxBase + 3 * (f0 + 1) + 1] = (float)(4 * tet_idx + 2);
        out[uvIdxBase + 3 * (f0 + 1) + 2] = (float)(4 * tet_idx + 3);
    }
}

// ---------------- host ----------------
template <typename T>
static void run_scan2(const T* in, T* out, int n, T* blockSums, T* totalOut,
                      hipStream_t stream) {
    int nb = (n + SCAN_TILE - 1) / SCAN_TILE;
    scanA_t<T><<<nb, SCAN_BLOCK, 0, stream>>>(in, out, n, blockSums);
    scanCf_t<T><<<nb, SCAN_BLOCK, 0, stream>>>(out, n, blockSums, nb, totalOut);
}

extern "C" void kernel_launch(void* const* d_in, const int* in_sizes, int n_in,
                              void* d_out, int out_size, void* d_ws, size_t ws_size,
                              hipStream_t stream) {
    const float* pos = (const float*)d_in[0];
    const float* sdf = (const float*)d_in[1];
    const int* tet = (const int*)d_in[2];
    int V = in_sizes[1];
    int T = in_sizes[2] / 4;
    float* out = (float*)d_out;

    int NB = (V + BIN_VR - 1) / BIN_VR;
    int gB = (T + TETS_PER_BLOCK - 1) / TETS_PER_BLOCK;
    int nHist = NB * gB;
    int NBlk = (V + 3) / 4;

    char* p = (char*)d_ws;
    auto alloc = [&](size_t bytes) -> void* {
        void* r = (void*)p;
        p += (bytes + 255) & ~(size_t)255;
        return r;
    };
    u8*  ti8           = (u8*) alloc((size_t)T);
    u64* tetPack       = (u64*)alloc((size_t)T * 8);
    u64* tetScan       = (u64*)alloc((size_t)T * 8);
    u32* blockHist     = (u32*)alloc((size_t)nHist * 4);
    u32* blockHistScan = (u32*)alloc((size_t)nHist * 4);
    u32* binData       = (u32*)alloc((size_t)6 * T * 4);   // reused as idxmap
    u32* binProv       = (u32*)alloc((size_t)6 * T * 4);
    u32* bucketCnt     = (u32*)alloc((size_t)V * 4);
    u32* bucketStart   = (u32*)alloc((size_t)V * 4);
    u32* binTotals     = (u32*)alloc((size_t)BIN_VR * 4);
    u32* crossScan     = (u32*)alloc((size_t)V * 4);
    uint2* rec2        = (uint2*)alloc(((size_t)6 * T + 4 * (size_t)V) * 8);
    u64* partials      = (u64*)alloc((size_t)NBlk * 8);
    u64* blockSums64   = (u64*)alloc(2048 * 8);
    u32* blockSums32   = (u32*)alloc(2048 * 4);
    u64* meta64        = (u64*)alloc(8 * 8);
    u32* NePtr         = (u32*)(meta64 + 4);
    u32* NeInstPtr     = (u32*)(meta64 + 5);
    u32* ticket        = (u32*)(meta64 + 6);

    // u8 idxmap (6T bytes) aliases binData (24T bytes): binData's last
    // reader is k_binscatter2, idxmap's first writer is k_sortverts.
    u8* idxmap = (u8*)binData;

    long long M = (2LL * T + 1) / 2;
    int Ngrid = (int)std::sqrt((double)M);
    while ((long long)Ngrid * Ngrid < M) ++Ngrid;
    if (Ngrid < 1) Ngrid = 1;
    long long uvFloats = 8LL * Ngrid * Ngrid;

    long long fw = (long long)Ngrid * Ngrid;          // >= T (M == T)
    if (fw < (long long)T) fw = T;
    int gFU = (int)((fw + 255) / 256);

    k_classify_hist<<<gB, 256, 0, stream>>>(tet, sdf, ti8, tetPack, blockHist,
                                            T, NB, gB);
    run_scan2<u64>(tetPack, tetScan, T, blockSums64, meta64, stream);
    run_scan2<u32>(blockHist, blockHistScan, nHist, blockSums32, NeInstPtr, stream);
    k_binfill<<<gB, 256, 0, stream>>>(tet, ti8, blockHistScan, binData, binProv,
                                      T, NB, gB);
    k_bincount2<<<NB, 256, 0, stream>>>(blockHistScan, NeInstPtr, binData,
                                        bucketCnt, bucketStart, binTotals,
                                        partials, ticket, NBlk, V, NB, gB);
    k_binscatter2<<<NB, 256, 0, stream>>>(blockHistScan, NeInstPtr, binData,
                                          binProv, binTotals, bucketStart,
                                          rec2, V, NB, gB);
    k_sortverts<<<NBlk, 256, 0, stream>>>(bucketCnt, bucketStart, rec2,
                                          idxmap, crossScan, partials, ticket,
                                          NePtr, pos, sdf, out, V, NBlk);
    k_faces<<<gFU, 256, 0, stream>>>(tet, ti8, tetScan, idxmap, crossScan,
                                     meta64, NePtr, out, T, Ngrid, uvFloats);
}

// Round 11
// 423.608 us; speedup vs baseline: 10.9279x; 10.9279x over previous
//
#include <hip/hip_runtime.h>
#include <cmath>

typedef unsigned long long u64;
typedef unsigned int u32;
typedef unsigned char u8;

#define SCAN_BLOCK 256
#define SCAN_ELEMS 8
#define SCAN_TILE (SCAN_BLOCK * SCAN_ELEMS)

// counting-sort bins: 512 vertices per bin (V=200000 -> NB=391 <= 512).
// record packing (mn&511)<<18 | mx requires V <= 2^18.
#define BIN_SHIFT 9
#define BIN_VR 512
#define TETS_PER_BLOCK 2048

__constant__ int d_NUMTRI[16] = {0,1,1,2,1,2,2,1,1,2,2,1,2,1,1,0};
__constant__ int d_TRI[16][6] = {
 {-1,-1,-1,-1,-1,-1},{1,0,2,-1,-1,-1},{4,0,3,-1,-1,-1},{1,4,2,1,3,4},
 {3,1,5,-1,-1,-1},{2,3,0,2,5,3},{1,4,0,1,5,4},{4,2,5,-1,-1,-1},
 {4,5,2,-1,-1,-1},{4,1,0,4,5,1},{3,2,0,3,5,2},{1,3,5,-1,-1,-1},
 {4,1,2,4,3,1},{3,0,4,-1,-1,-1},{2,0,1,-1,-1,-1},{-1,-1,-1,-1,-1,-1}};
__constant__ int d_E0[6] = {0,0,0,1,1,2};
__constant__ int d_E1[6] = {1,2,3,2,3,3};

// ---------------- exclusive scan -------------------------------------------
// R10 lesson (global): decoupled-lookback single-kernel scans serialize on
// MI355X (agent-scope FINC chain ~90ns/block => 4.4ms for 50k blocks).
// Stick to multi-dispatch scans.
// NOTE: tet m1/m2 scan MUST be u64 — running m1 total needs 19 bits packed
// at bit 21 (overflowed u32 in an early round).
template <typename T>
__global__ void scanA_t(const T* in, T* out, int n, T* blockSums) {
    __shared__ T tsum[SCAN_BLOCK];
    int tbase = blockIdx.x * SCAN_TILE + threadIdx.x * SCAN_ELEMS;
    T vals[SCAN_ELEMS];
    T run = 0;
    for (int k = 0; k < SCAN_ELEMS; ++k) {
        int i = tbase + k;
        T v = (i < n) ? in[i] : (T)0;
        vals[k] = run;
        run += v;
    }
    tsum[threadIdx.x] = run;
    __syncthreads();
    for (int off = 1; off < SCAN_BLOCK; off <<= 1) {
        T v = (threadIdx.x >= (unsigned)off) ? tsum[threadIdx.x - off] : (T)0;
        __syncthreads();
        tsum[threadIdx.x] += v;
        __syncthreads();
    }
    T texcl = (threadIdx.x == 0) ? (T)0 : tsum[threadIdx.x - 1];
    for (int k = 0; k < SCAN_ELEMS; ++k) {
        int i = tbase + k;
        if (i < n) out[i] = texcl + vals[k];
    }
    if (threadIdx.x == SCAN_BLOCK - 1) blockSums[blockIdx.x] = tsum[SCAN_BLOCK - 1];
}

// Fused scanB+scanC: every block redundantly scans the <=2048 blockSums in
// LDS and adds its exclusive prefix. Block 0 also emits the grand total.
template <typename T>
__global__ void scanCf_t(T* out, int n, const T* bs, int nb, T* totalOut) {
    __shared__ T sh[2048];
    for (int i = threadIdx.x; i < 2048; i += 256) sh[i] = (i < nb) ? bs[i] : (T)0;
    __syncthreads();
    for (int off = 1; off < 2048; off <<= 1) {
        T v[8];
        for (int k = 0; k < 8; ++k) {
            int i = threadIdx.x + k * 256;
            v[k] = (i >= off) ? sh[i - off] : (T)0;
        }
        __syncthreads();
        for (int k = 0; k < 8; ++k) sh[threadIdx.x + k * 256] += v[k];
        __syncthreads();
    }
    if (totalOut && blockIdx.x == 0 && threadIdx.x == 0)
        *totalOut = (nb > 0) ? sh[nb - 1] : (T)0;
    T add = (blockIdx.x == 0) ? (T)0 : sh[blockIdx.x - 1];
    int base = blockIdx.x * SCAN_TILE;
    int end = base + SCAN_TILE; if (end > n) end = n;
    for (int i = base + threadIdx.x; i < end; i += SCAN_BLOCK) out[i] += add;
}

// Dual scanA: one dispatch covers BOTH independent post-classify scans
// (tetPack u64 over T in blocks [0,nbT); blockHist u32 over nHist in blocks
// [nbT, nbT+nbH)). Saves a dispatch boundary.
__global__ void k_scanA_dual(const u64* in64, u64* out64, int n64, u64* bs64,
                             const u32* in32, u32* out32, int n32, u32* bs32,
                             int nbT) {
    __shared__ u64 tsum[SCAN_BLOCK];
    if ((int)blockIdx.x < nbT) {
        int tbase = blockIdx.x * SCAN_TILE + threadIdx.x * SCAN_ELEMS;
        u64 vals[SCAN_ELEMS]; u64 run = 0;
        for (int k = 0; k < SCAN_ELEMS; ++k) {
            int i = tbase + k;
            u64 v = (i < n64) ? in64[i] : 0ull;
            vals[k] = run; run += v;
        }
        tsum[threadIdx.x] = run;
        __syncthreads();
        for (int off = 1; off < SCAN_BLOCK; off <<= 1) {
            u64 v = (threadIdx.x >= (unsigned)off) ? tsum[threadIdx.x - off] : 0ull;
            __syncthreads();
            tsum[threadIdx.x] += v;
            __syncthreads();
        }
        u64 texcl = (threadIdx.x == 0) ? 0ull : tsum[threadIdx.x - 1];
        for (int k = 0; k < SCAN_ELEMS; ++k) {
            int i = tbase + k;
            if (i < n64) out64[i] = texcl + vals[k];
        }
        if (threadIdx.x == SCAN_BLOCK - 1) bs64[blockIdx.x] = tsum[SCAN_BLOCK - 1];
    } else {
        int blk = (int)blockIdx.x - nbT;
        int tbase = blk * SCAN_TILE + threadIdx.x * SCAN_ELEMS;
        u32 vals[SCAN_ELEMS]; u32 run = 0;
        for (int k = 0; k < SCAN_ELEMS; ++k) {
            int i = tbase + k;
            u32 v = (i < n32) ? in32[i] : 0u;
            vals[k] = run; run += v;
        }
        tsum[threadIdx.x] = (u64)run;
        __syncthreads();
        for (int off = 1; off < SCAN_BLOCK; off <<= 1) {
            u64 v = (threadIdx.x >= (unsigned)off) ? tsum[threadIdx.x - off] : 0ull;
            __syncthreads();
            tsum[threadIdx.x] += v;
            __syncthreads();
        }
        u32 texcl = (threadIdx.x == 0) ? 0u : (u32)tsum[threadIdx.x - 1];
        for (int k = 0; k < SCAN_ELEMS; ++k) {
            int i = tbase + k;
            if (i < n32) out32[i] = texcl + vals[k];
        }
        if (threadIdx.x == SCAN_BLOCK - 1) bs32[blk] = (u32)tsum[SCAN_BLOCK - 1];
    }
}

// Dual scanCf: same block-range split for the fixup passes.
__global__ void k_scanCf_dual(u64* out64, int n64, const u64* bs64, int nb64,
                              u64* total64,
                              u32* out32, int n32, const u32* bs32, int nb32,
                              u32* total32, int nbT) {
    __shared__ u64 sh[2048];        // 16KB
    if ((int)blockIdx.x < nbT) {
        for (int i = threadIdx.x; i < 2048; i += 256)
            sh[i] = (i < nb64) ? bs64[i] : 0ull;
        __syncthreads();
        for (int off = 1; off < 2048; off <<= 1) {
            u64 v[8];
            for (int k = 0; k < 8; ++k) {
                int i = threadIdx.x + k * 256;
                v[k] = (i >= off) ? sh[i - off] : 0ull;
            }
            __syncthreads();
            for (int k = 0; k < 8; ++k) sh[threadIdx.x + k * 256] += v[k];
            __syncthreads();
        }
        if (total64 && blockIdx.x == 0 && threadIdx.x == 0)
            *total64 = (nb64 > 0) ? sh[nb64 - 1] : 0ull;
        u64 add = (blockIdx.x == 0) ? 0ull : sh[blockIdx.x - 1];
        int base = blockIdx.x * SCAN_TILE;
        int end = base + SCAN_TILE; if (end > n64) end = n64;
        for (int i = base + threadIdx.x; i < end; i += SCAN_BLOCK) out64[i] += add;
    } else {
        int blk = (int)blockIdx.x - nbT;
        for (int i = threadIdx.x; i < 2048; i += 256)
            sh[i] = (i < nb32) ? (u64)bs32[i] : 0ull;
        __syncthreads();
        for (int off = 1; off < 2048; off <<= 1) {
            u64 v[8];
            for (int k = 0; k < 8; ++k) {
                int i = threadIdx.x + k * 256;
                v[k] = (i >= off) ? sh[i - off] : 0ull;
            }
            __syncthreads();
            for (int k = 0; k < 8; ++k) sh[threadIdx.x + k * 256] += v[k];
            __syncthreads();
        }
        if (total32 && blk == 0 && threadIdx.x == 0)
            *total32 = (nb32 > 0) ? (u32)sh[nb32 - 1] : 0u;
        u32 add = (blk == 0) ? 0u : (u32)sh[blk - 1];
        int base = blk * SCAN_TILE;
        int end = base + SCAN_TILE; if (end > n32) end = n32;
        for (int i = base + threadIdx.x; i < end; i += SCAN_BLOCK) out32[i] += add;
    }
}

// ---------------- pipeline ----------------
// Pass A: classify tets + per-block LDS histogram of crossing edges over
// bins (binned structure is load-bearing: R6's direct global scatter = 64B
// write-allocate per 8B record = 285us). Zeroes bigCnt.
__global__ __launch_bounds__(256) void k_classify_hist(
    const int* tet, const float* sdf, u8* ti8, u64* tetPack,
    u32* blockHist, u32* bigCnt, int T, int NB, int gB) {
    if (blockIdx.x == 0 && threadIdx.x == 0) *bigCnt = 0;
    __shared__ u32 hist[BIN_VR];
    for (int i = threadIdx.x; i < NB; i += 256) hist[i] = 0;
    __syncthreads();
    int base = blockIdx.x * TETS_PER_BLOCK;
    for (int it = 0; it < TETS_PER_BLOCK / 256; ++it) {
        int t = base + it * 256 + threadIdx.x;
        if (t < T) {
            int4 q = reinterpret_cast<const int4*>(tet)[t];
            int ti = (sdf[q.x] > 0.0f ? 1 : 0) | (sdf[q.y] > 0.0f ? 2 : 0) |
                     (sdf[q.z] > 0.0f ? 4 : 0) | (sdf[q.w] > 0.0f ? 8 : 0);
            ti8[t] = (u8)ti;
            int nt = d_NUMTRI[ti];
            tetPack[t] = ((u64)(nt == 1 ? 1 : 0) << 21) | (u64)(nt == 2 ? 1 : 0);
            if (nt != 0) {
                int idx[4] = {q.x, q.y, q.z, q.w};
                #pragma unroll
                for (int e = 0; e < 6; ++e) {
                    int e0 = d_E0[e], e1 = d_E1[e];
                    if (((ti >> e0) ^ (ti >> e1)) & 1) {
                        int a = idx[e0], b = idx[e1];
                        int mn = a < b ? a : b;
                        atomicAdd(&hist[mn >> BIN_SHIFT], 1u);
                    }
                }
            }
        }
    }
    __syncthreads();
    for (int i = threadIdx.x; i < NB; i += 256)
        blockHist[(size_t)i * gB + blockIdx.x] = hist[i];
}

// Pass B: block-local LDS cursors hand out contiguous slots in the
// bin-sorted record array. ONE u64 record = prov<<32 | ((mn&511)<<18 | mx)
// (single 8B scattered stream instead of two 4B streams — R11).
__global__ __launch_bounds__(256) void k_binfill(
    const int* tet, const u8* ti8, const u32* blockHistScan,
    u64* binRec, int T, int NB, int gB) {
    __shared__ u32 cur[BIN_VR];
    for (int i = threadIdx.x; i < NB; i += 256)
        cur[i] = blockHistScan[(size_t)i * gB + blockIdx.x];
    __syncthreads();
    int base = blockIdx.x * TETS_PER_BLOCK;
    for (int it = 0; it < TETS_PER_BLOCK / 256; ++it) {
        int t = base + it * 256 + threadIdx.x;
        if (t < T) {
            int ti = ti8[t];
            if (d_NUMTRI[ti] != 0) {
                int4 q = reinterpret_cast<const int4*>(tet)[t];
                int idx[4] = {q.x, q.y, q.z, q.w};
                #pragma unroll
                for (int e = 0; e < 6; ++e) {
                    int e0 = d_E0[e], e1 = d_E1[e];
                    if (((ti >> e0) ^ (ti >> e1)) & 1) {
                        int a = idx[e0], b = idx[e1];
                        int mn = a < b ? a : b;
                        int mx = a < b ? b : a;
                        u32 slot = atomicAdd(&cur[mn >> BIN_SHIFT], 1u);
                        u32 rec = ((u32)(mn & (BIN_VR - 1)) << 18) | (u32)mx;
                        u32 pv = 6u * (u32)t + (u32)e;
                        binRec[slot] = ((u64)pv << 32) | (u64)rec;
                    }
                }
            }
        }
    }
}

// one block per bin: LDS histogram over the bin's records, then LDS scan of
// the 512 padded counts -> bucketCnt + within-bin offsets + per-bin total.
__global__ __launch_bounds__(256) void k_bincount2(
    const u32* blockHistScan, const u32* totalPtr, const u64* binRec,
    u32* bucketCnt, u32* bucketStart, u32* binTotals, int V, int NB, int gB) {
    int bin = blockIdx.x;
    __shared__ u32 hist[BIN_VR];
    __shared__ u32 sc[BIN_VR];
    for (int i = threadIdx.x; i < BIN_VR; i += 256) hist[i] = 0;
    __syncthreads();
    u32 s = blockHistScan[(size_t)bin * gB];
    u32 e = (bin + 1 < NB) ? blockHistScan[(size_t)(bin + 1) * gB] : *totalPtr;
    for (u32 i = s + threadIdx.x; i < e; i += 256)
        atomicAdd(&hist[((u32)binRec[i]) >> 18], 1u);
    __syncthreads();
    int t0 = threadIdx.x, t1 = threadIdx.x + 256;
    sc[t0] = (hist[t0] + 3u) & ~3u;          // pad4; empty buckets stay 0
    sc[t1] = (hist[t1] + 3u) & ~3u;
    __syncthreads();
    for (int off = 1; off < BIN_VR; off <<= 1) {
        u32 v0 = (t0 >= off) ? sc[t0 - off] : 0u;
        u32 v1 = (t1 >= off) ? sc[t1 - off] : 0u;
        __syncthreads();
        sc[t0] += v0; sc[t1] += v1;          // inclusive scan
        __syncthreads();
    }
    int vbase = bin << BIN_SHIFT;
    for (int i = threadIdx.x; i < BIN_VR; i += 256) {
        int v = vbase + i;
        if (v < V) {
            u32 h = hist[i];
            bucketCnt[v] = h;
            bucketStart[v] = sc[i] - ((h + 3u) & ~3u);   // local excl offset
        }
    }
    if (threadIdx.x == 0) binTotals[bin] = sc[BIN_VR - 1];
}

// one block per bin: redundant LDS scan of the <=512 bin totals -> binBase;
// finalize bucketStart (absolute), then scatter (mx,prov) uint2 records into
// the bin's L2-resident window via LDS cursors.
__global__ __launch_bounds__(256) void k_binscatter2(
    const u32* blockHistScan, const u32* totalPtr, const u64* binRec,
    const u32* binTotals, u32* bucketStart, uint2* rec2,
    int V, int NB, int gB) {
    int bin = blockIdx.x;
    __shared__ u32 bt[BIN_VR];
    __shared__ u32 cur[BIN_VR];
    int t0 = threadIdx.x, t1 = threadIdx.x + 256;
    bt[t0] = (t0 < NB) ? binTotals[t0] : 0u;
    bt[t1] = (t1 < NB) ? binTotals[t1] : 0u;
    __syncthreads();
    for (int off = 1; off < BIN_VR; off <<= 1) {
        u32 v0 = (t0 >= off) ? bt[t0 - off] : 0u;
        u32 v1 = (t1 >= off) ? bt[t1 - off] : 0u;
        __syncthreads();
        bt[t0] += v0; bt[t1] += v1;
        __syncthreads();
    }
    u32 binBase = (bin == 0) ? 0u : bt[bin - 1];
    int vbase = bin << BIN_SHIFT;
    for (int i = threadIdx.x; i < BIN_VR; i += 256) {
        int v = vbase + i;
        if (v < V) {
            u32 a = binBase + bucketStart[v];
            bucketStart[v] = a;
            cur[i] = a;
        } else cur[i] = 0u;
    }
    __syncthreads();
    u32 s = blockHistScan[(size_t)bin * gB];
    u32 e = (bin + 1 < NB) ? blockHistScan[(size_t)(bin + 1) * gB] : *totalPtr;
    for (u32 i = s + threadIdx.x; i < e; i += 256) {
        u64 r = binRec[i];
        u32 rec = (u32)r;
        u32 pv = (u32)(r >> 32);
        u32 slot = atomicAdd(&cur[rec >> 18], 1u);
        rec2[slot] = make_uint2(rec & 0x3FFFFu, pv);
    }
}

// HOT sort+dedup — R2/R7 measured-best structure: ONE bucket per 64-lane
// wave (wave-UNIFORM n -> SGPR loop), 4 buckets/256-block, zero LDS, no
// barriers. u8 idxmap (dedup idx < 256); plain stores (NT = R3 disaster).
__global__ __launch_bounds__(256) void k_sortdedup(
    const u32* bucketCnt, const u32* bucketStart, uint2* rec2,
    u8* idxmap, u32* crossCnt, u32* bigList, u32* bigCnt, int V)
{
    int v = blockIdx.x * 4 + (threadIdx.x >> 6);
    if (v >= V) return;
    int lane = threadIdx.x & 63;
    int n = (int)bucketCnt[v];
    if (n == 0) { if (lane == 0) crossCnt[v] = 0; return; }
    if (n > 64) {
        if (lane == 0) bigList[atomicAdd(bigCnt, 1u)] = (u32)v;
        return;
    }
    long long start = (long long)bucketStart[v];
    uint2 rp = (lane < n) ? rec2[start + lane] : make_uint2(0xFFFFFFFFu, 0u);
    u32 key = rp.x, prov = rp.y;
    int rank = 0;
    for (int j = 0; j < n; ++j) {               // wave-uniform bound, avg ~15
        u32 kj = (u32)__shfl((int)key, j);
        rank += (kj < key || (kj == key && j < lane)) ? 1 : 0;
    }
    u32 sorted = (u32)__builtin_amdgcn_ds_permute(rank << 2, (int)key);
    u32 prev = (u32)__shfl((int)sorted, lane - 1);
    bool nf = (lane < n) && (lane == 0 || prev != sorted);
    u64 m = __ballot(nf);
    int idx = __popcll(m & ((1ull << lane) - 1ull));
    if (nf) rec2[start + idx].x = sorted;
    int ldSorted = nf ? idx : idx - 1;          // dedup idx at sorted pos lane
    int ldOrig = __shfl(ldSorted, rank);        // my record sits at pos rank
    if (lane < n) idxmap[prov] = (u8)ldOrig;
    if (lane == 0) crossCnt[v] = (u32)__popcll(m);
}

// Overflow (64<n<=256, rare low-index buckets): full wave per bucket,
// register-chunked (4x64) two-pass shfl rank/dedup — no LDS, no serial work
// (R4 lesson: lane-0 insertion sort on real buckets = 207us tail). Serial
// remains only for n>256 (needs a vertex in ~85+ tets; P~0).
__global__ __launch_bounds__(256) void k_sortbig(
    const u32* bigList, const u32* bigCnt, const u32* bucketCnt,
    const u32* bucketStart, uint2* rec2, u8* idxmap, u32* crossCnt)
{
    int nbig = (int)*bigCnt;
    int lane = threadIdx.x & 63;
    int wave = (blockIdx.x << 2) + (threadIdx.x >> 6);
    int stride = gridDim.x << 2;
    for (int b = wave; b < nbig; b += stride) {
        int v = (int)bigList[b];
        int n = (int)bucketCnt[v];
        long long start = (long long)bucketStart[v];
        if (n <= 256) {
            int chunks = (n + 63) >> 6;         // 1..4
            u32 key[4], prov[4], kf[4];
            int myi[4];
            #pragma unroll
            for (int c = 0; c < 4; ++c) {
                myi[c] = (c << 6) + lane;
                key[c] = 0xFFFFFFFFu; prov[c] = 0u;
                if (c < chunks && myi[c] < n) {
                    uint2 rp = rec2[start + myi[c]];
                    key[c] = rp.x; prov[c] = rp.y;
                }
            }
            bool tie[4] = {false, false, false, false};
            #pragma unroll
            for (int c2 = 0; c2 < 4; ++c2) {
                if (c2 < chunks) {
                    int base2 = c2 << 6;
                    int lim = n - base2; if (lim > 64) lim = 64;
                    for (int j = 0; j < lim; ++j) {
                        u32 kj = (u32)__shfl((int)key[c2], j);
                        int jg = base2 + j;
                        #pragma unroll
                        for (int c = 0; c < 4; ++c) {
                            if (c < chunks)
                                tie[c] = tie[c] | (kj == key[c] && jg < myi[c]);
                        }
                    }
                }
            }
            u32 uq = 0;
            #pragma unroll
            for (int c = 0; c < 4; ++c) {
                bool isf = (c < chunks) && (myi[c] < n) && !tie[c];
                kf[c] = key[c] | (isf ? 0x80000000u : 0u);
                u64 bal = __ballot(isf);
                uq += (u32)__popcll(bal);
            }
            int uless[4] = {0, 0, 0, 0};
            #pragma unroll
            for (int c2 = 0; c2 < 4; ++c2) {
                if (c2 < chunks) {
                    int base2 = c2 << 6;
                    int lim = n - base2; if (lim > 64) lim = 64;
                    for (int j = 0; j < lim; ++j) {
                        u32 kfj = (u32)__shfl((int)kf[c2], j);
                        u32 kj = kfj & 0x7FFFFFFFu;
                        bool fj = (kfj & 0x80000000u) != 0u;
                        #pragma unroll
                        for (int c = 0; c < 4; ++c) {
                            if (c < chunks)
                                uless[c] += (fj && kj < key[c]) ? 1 : 0;
                        }
                    }
                }
            }
            #pragma unroll
            for (int c = 0; c < 4; ++c) {
                if (c < chunks && myi[c] < n) {
                    if (kf[c] & 0x80000000u)
                        rec2[start + uless[c]].x = key[c];
                    idxmap[prov[c]] = (u8)uless[c];
                }
            }
            if (lane == 0) crossCnt[v] = uq;
        } else if (lane == 0) {
            for (int i = 1; i < n; ++i) {
                uint2 kk = rec2[start + i];
                int j = i - 1;
                while (j >= 0 && rec2[start + j].x > kk.x) {
                    rec2[start + j + 1] = rec2[start + j]; --j;
                }
                rec2[start + j + 1] = kk;
            }
            int uc = 0; u32 prev = 0xFFFFFFFFu;
            for (int i = 0; i < n; ++i) {
                uint2 r = rec2[start + i];
                if (r.x != prev) { rec2[start + uc].x = r.x; ++uc; prev = r.x; }
                idxmap[r.y] = (u8)(uc - 1);
            }
            crossCnt[v] = (u32)uc;
        }
    }
}

// 32-lane segments, 8 buckets per 256-block; lane i -> unique crossing edge
// i -> vertex crossScan[v]+i. Strided loop handles u>32.
__global__ __launch_bounds__(256) void k_verts(
    const u32* crossCnt, const u32* bucketStart, const uint2* rec2, const u32* crossScan,
    const float* pos, const float* sdf, float* out, int V)
{
    int v = blockIdx.x * 8 + (threadIdx.x >> 5);
    if (v >= V) return;
    int slane = threadIdx.x & 31;
    int u = (int)crossCnt[v];
    if (u == 0) return;
    long long start = (long long)bucketStart[v];
    int cBase = (int)crossScan[v];
    float s0 = sdf[v];
    float p0x = pos[3 * v], p0y = pos[3 * v + 1], p0z = pos[3 * v + 2];
    for (int i = slane; i < u; i += 32) {
        int b = (int)rec2[start + i].x;
        long long k = cBase + i;
        float s1 = sdf[b];
        float d = s0 - s1;
        float w0 = -s1 / d, w1 = s0 / d;
        out[3 * k + 0] = p0x * w0 + pos[3 * b + 0] * w1;
        out[3 * k + 1] = p0y * w0 + pos[3 * b + 1] * w1;
        out[3 * k + 2] = p0z * w0 + pos[3 * b + 2] * w1;
    }
}

// faces + uv_idx + fused uv grid (Ngrid^2 >= T since M == T). Edge->vertex
// id: u8 idx_map[6t+e] = local dedup index; global id = crossScan[a]+local.
__global__ void k_faces(const int* tet, const u8* ti8, const u64* tetScan,
                        const u8* idxmap, const u32* crossScan,
                        const u64* meta0, const u32* NePtr,
                        float* out, int T, int Ngrid, long long uvFloats)
{
    int t = blockIdx.x * 256 + threadIdx.x;
    int uvTotal = Ngrid * Ngrid;
    if (t >= T && t >= uvTotal) return;

    u64 tot = *meta0;
    int C1 = (int)((tot >> 21) & 0x1fffffull);
    int C2 = (int)(tot & 0x1fffffull);
    int Ne = (int)*NePtr;
    long long facesBase = 3LL * Ne;
    long long F = (long long)C1 + 2LL * C2;
    long long uvBase = facesBase + 3LL * F;
    long long uvIdxBase = uvBase + uvFloats;

    if (t < uvTotal) {          // fused uv-grid write
        int i = t / Ngrid, j = t % Ngrid;
        double step = (Ngrid > 1) ? (1.0 - 1.0 / (double)Ngrid) / (double)(Ngrid - 1) : 0.0;
        float x = (float)((double)j * step);
        float y = (float)((double)i * step);
        float pad = (float)(0.9 / (double)Ngrid);
        long long o = uvBase + 8LL * t;
        out[o + 0] = x;       out[o + 1] = y;
        out[o + 2] = x + pad; out[o + 3] = y;
        out[o + 4] = x + pad; out[o + 5] = y + pad;
        out[o + 6] = x;       out[o + 7] = y + pad;
    }
    if (t >= T) return;

    int ti = ti8[t];
    int nt = d_NUMTRI[ti];
    if (nt == 0) return;

    int4 q = reinterpret_cast<const int4*>(tet)[t];
    int idx[4] = {q.x, q.y, q.z, q.w};
    const unsigned short* imp =
        reinterpret_cast<const unsigned short*>(idxmap + 6ll * t);
    unsigned short w0 = imp[0], w1 = imp[1], w2 = imp[2];
    u32 im[6] = {(u32)(w0 & 0xFF), (u32)(w0 >> 8),
                 (u32)(w1 & 0xFF), (u32)(w1 >> 8),
                 (u32)(w2 & 0xFF), (u32)(w2 >> 8)};
    const int* row = d_TRI[ti];

    int emap[6];
    unsigned done = 0;
    float fv[6];
    #pragma unroll
    for (int j = 0; j < 6; ++j) {
        if (j >= 3 * nt) break;
        int e = row[j];
        if (!((done >> e) & 1)) {
            done |= 1u << e;
            int a = idx[d_E0[e]], b = idx[d_E1[e]];
            if (b < a) a = b;                  // a = min endpoint = bucket
            emap[e] = (int)crossScan[a] + (int)im[e];
        }
        fv[j] = (float)emap[e];
    }

    u64 sc = tetScan[t];
    int r1s = (int)((sc >> 21) & 0x1fffffull);
    int r2s = (int)(sc & 0x1fffffull);
    int tet_idx = (t / Ngrid) * Ngrid + (t % Ngrid);

    if (nt == 1) {
        long long f = r1s;
        out[facesBase + 3 * f + 0] = fv[0];
        out[facesBase + 3 * f + 1] = fv[1];
        out[facesBase + 3 * f + 2] = fv[2];
        out[uvIdxBase + 3 * f + 0] = (float)(4 * tet_idx);
        out[uvIdxBase + 3 * f + 1] = (float)(4 * tet_idx + 1);
        out[uvIdxBase + 3 * f + 2] = (float)(4 * tet_idx + 2);
    } else {
        long long f0 = (long long)C1 + 2LL * r2s;
        out[facesBase + 3 * f0 + 0] = fv[0];
        out[facesBase + 3 * f0 + 1] = fv[1];
        out[facesBase + 3 * f0 + 2] = fv[2];
        out[facesBase + 3 * (f0 + 1) + 0] = fv[3];
        out[facesBase + 3 * (f0 + 1) + 1] = fv[4];
        out[facesBase + 3 * (f0 + 1) + 2] = fv[5];
        out[uvIdxBase + 3 * f0 + 0] = (float)(4 * tet_idx);
        out[uvIdxBase + 3 * f0 + 1] = (float)(4 * tet_idx + 1);
        out[uvIdxBase + 3 * f0 + 2] = (float)(4 * tet_idx + 2);
        out[uvIdxBase + 3 * (f0 + 1) + 0] = (float)(4 * tet_idx);
        out[uvIdxBase + 3 * (f0 + 1) + 1] = (float)(4 * tet_idx + 2);
        out[uvIdxBase + 3 * (f0 + 1) + 2] = (float)(4 * tet_idx + 3);
    }
}

// ---------------- host ----------------
template <typename T>
static void run_scan2(const T* in, T* out, int n, T* blockSums, T* totalOut,
                      hipStream_t stream) {
    int nb = (n + SCAN_TILE - 1) / SCAN_TILE;
    scanA_t<T><<<nb, SCAN_BLOCK, 0, stream>>>(in, out, n, blockSums);
    scanCf_t<T><<<nb, SCAN_BLOCK, 0, stream>>>(out, n, blockSums, nb, totalOut);
}

extern "C" void kernel_launch(void* const* d_in, const int* in_sizes, int n_in,
                              void* d_out, int out_size, void* d_ws, size_t ws_size,
                              hipStream_t stream) {
    const float* pos = (const float*)d_in[0];
    const float* sdf = (const float*)d_in[1];
    const int* tet = (const int*)d_in[2];
    int V = in_sizes[1];
    int T = in_sizes[2] / 4;
    float* out = (float*)d_out;

    int NB = (V + BIN_VR - 1) / BIN_VR;
    int gB = (T + TETS_PER_BLOCK - 1) / TETS_PER_BLOCK;
    int nHist = NB * gB;

    char* p = (char*)d_ws;
    auto alloc = [&](size_t bytes) -> void* {
        void* r = (void*)p;
        p += (bytes + 255) & ~(size_t)255;
        return r;
    };
    u8*  ti8           = (u8*) alloc((size_t)T);
    u64* tetPack       = (u64*)alloc((size_t)T * 8);
    u64* tetScan       = (u64*)alloc((size_t)T * 8);
    u32* blockHist     = (u32*)alloc((size_t)nHist * 4);
    u32* blockHistScan = (u32*)alloc((size_t)nHist * 4);
    u64* binRec        = (u64*)alloc((size_t)6 * T * 8);   // reused as idxmap
    u32* bucketCnt     = (u32*)alloc((size_t)V * 4);
    u32* bucketStart   = (u32*)alloc((size_t)V * 4);
    u32* binTotals     = (u32*)alloc((size_t)BIN_VR * 4);
    u32* crossCnt      = (u32*)alloc((size_t)V * 4);
    u32* crossScan     = (u32*)alloc((size_t)V * 4);
    uint2* rec2        = (uint2*)alloc(((size_t)6 * T + 4 * (size_t)V) * 8);
    u32* bigList       = (u32*)alloc((size_t)V * 4);
    u64* blockSums64   = (u64*)alloc(2048 * 8);
    u32* blockSums32   = (u32*)alloc(2048 * 4);
    u64* meta64        = (u64*)alloc(8 * 8);
    u32* NePtr         = (u32*)(meta64 + 4);
    u32* NeInstPtr     = (u32*)(meta64 + 5);
    u32* bigCnt        = (u32*)(meta64 + 6);

    // u8 idxmap (6T bytes) aliases binRec (48T bytes): binRec's last reader
    // is k_binscatter2, idxmap's first writer is k_sortdedup.
    u8* idxmap = (u8*)binRec;

    long long M = (2LL * T + 1) / 2;
    int Ngrid = (int)std::sqrt((double)M);
    while ((long long)Ngrid * Ngrid < M) ++Ngrid;
    if (Ngrid < 1) Ngrid = 1;
    long long uvFloats = 8LL * Ngrid * Ngrid;

    int gV4 = (V + 3) / 4;
    int gV8 = (V + 7) / 8;
    long long fw = (long long)Ngrid * Ngrid;          // >= T (M == T)
    if (fw < (long long)T) fw = T;
    int gFU = (int)((fw + 255) / 256);

    int nbT = (T + SCAN_TILE - 1) / SCAN_TILE;
    int nbH = (nHist + SCAN_TILE - 1) / SCAN_TILE;

    k_classify_hist<<<gB, 256, 0, stream>>>(tet, sdf, ti8, tetPack, blockHist,
                                            bigCnt, T, NB, gB);
    // fused dual scan: tetPack (u64, T) + blockHist (u32, nHist)
    k_scanA_dual<<<nbT + nbH, SCAN_BLOCK, 0, stream>>>(
        tetPack, tetScan, T, blockSums64,
        blockHist, blockHistScan, nHist, blockSums32, nbT);
    k_scanCf_dual<<<nbT + nbH, SCAN_BLOCK, 0, stream>>>(
        tetScan, T, blockSums64, nbT, meta64,
        blockHistScan, nHist, blockSums32, nbH, NeInstPtr, nbT);
    k_binfill<<<gB, 256, 0, stream>>>(tet, ti8, blockHistScan, binRec,
                                      T, NB, gB);
    k_bincount2<<<NB, 256, 0, stream>>>(blockHistScan, NeInstPtr, binRec,
                                        bucketCnt, bucketStart, binTotals,
                                        V, NB, gB);
    k_binscatter2<<<NB, 256, 0, stream>>>(blockHistScan, NeInstPtr, binRec,
                                          binTotals, bucketStart, rec2,
                                          V, NB, gB);
    k_sortdedup<<<gV4, 256, 0, stream>>>(bucketCnt, bucketStart, rec2,
                                         idxmap, crossCnt, bigList, bigCnt, V);
    k_sortbig<<<1024, 256, 0, stream>>>(bigList, bigCnt, bucketCnt, bucketStart,
                                        rec2, idxmap, crossCnt);
    run_scan2<u32>(crossCnt, crossScan, V, blockSums32, NePtr, stream);
    k_verts<<<gV8, 256, 0, stream>>>(crossCnt, bucketStart, rec2, crossScan,
                                     pos, sdf, out, V);
    k_faces<<<gFU, 256, 0, stream>>>(tet, ti8, tetScan, idxmap, crossScan,
                                     meta64, NePtr, out, T, Ngrid, uvFloats);
}

// Round 12
// 410.957 us; speedup vs baseline: 11.2644x; 1.0308x over previous
//
#include <hip/hip_runtime.h>
#include <cmath>

typedef unsigned long long u64;
typedef unsigned int u32;
typedef unsigned char u8;

#define SCAN_BLOCK 256
#define SCAN_ELEMS 8
#define SCAN_TILE (SCAN_BLOCK * SCAN_ELEMS)

// counting-sort bins: 512 vertices per bin (V=200000 -> NB=391 <= 512).
// record packing (mn&511)<<18 | mx requires V <= 2^18.
#define BIN_SHIFT 9
#define BIN_VR 512
#define TETS_PER_BLOCK 2048

__constant__ int d_NUMTRI[16] = {0,1,1,2,1,2,2,1,1,2,2,1,2,1,1,0};
__constant__ int d_TRI[16][6] = {
 {-1,-1,-1,-1,-1,-1},{1,0,2,-1,-1,-1},{4,0,3,-1,-1,-1},{1,4,2,1,3,4},
 {3,1,5,-1,-1,-1},{2,3,0,2,5,3},{1,4,0,1,5,4},{4,2,5,-1,-1,-1},
 {4,5,2,-1,-1,-1},{4,1,0,4,5,1},{3,2,0,3,5,2},{1,3,5,-1,-1,-1},
 {4,1,2,4,3,1},{3,0,4,-1,-1,-1},{2,0,1,-1,-1,-1},{-1,-1,-1,-1,-1,-1}};
__constant__ int d_E0[6] = {0,0,0,1,1,2};
__constant__ int d_E1[6] = {1,2,3,2,3,3};

// ---------------- exclusive scan -------------------------------------------
// R10 lesson (global): decoupled-lookback single-kernel scans serialize on
// MI355X (agent-scope FINC chain ~90ns/block => 4.4ms for 50k blocks).
// Stick to multi-dispatch scans.
// NOTE: tet m1/m2 scan MUST be u64 — running m1 total needs 19 bits packed
// at bit 21 (overflowed u32 in an early round).
template <typename T>
__global__ void scanA_t(const T* in, T* out, int n, T* blockSums) {
    __shared__ T tsum[SCAN_BLOCK];
    int tbase = blockIdx.x * SCAN_TILE + threadIdx.x * SCAN_ELEMS;
    T vals[SCAN_ELEMS];
    T run = 0;
    for (int k = 0; k < SCAN_ELEMS; ++k) {
        int i = tbase + k;
        T v = (i < n) ? in[i] : (T)0;
        vals[k] = run;
        run += v;
    }
    tsum[threadIdx.x] = run;
    __syncthreads();
    for (int off = 1; off < SCAN_BLOCK; off <<= 1) {
        T v = (threadIdx.x >= (unsigned)off) ? tsum[threadIdx.x - off] : (T)0;
        __syncthreads();
        tsum[threadIdx.x] += v;
        __syncthreads();
    }
    T texcl = (threadIdx.x == 0) ? (T)0 : tsum[threadIdx.x - 1];
    for (int k = 0; k < SCAN_ELEMS; ++k) {
        int i = tbase + k;
        if (i < n) out[i] = texcl + vals[k];
    }
    if (threadIdx.x == SCAN_BLOCK - 1) blockSums[blockIdx.x] = tsum[SCAN_BLOCK - 1];
}

// Fused scanB+scanC: every block redundantly scans the <=2048 blockSums in
// LDS and adds its exclusive prefix. Block 0 also emits the grand total.
template <typename T>
__global__ void scanCf_t(T* out, int n, const T* bs, int nb, T* totalOut) {
    __shared__ T sh[2048];
    for (int i = threadIdx.x; i < 2048; i += 256) sh[i] = (i < nb) ? bs[i] : (T)0;
    __syncthreads();
    for (int off = 1; off < 2048; off <<= 1) {
        T v[8];
        for (int k = 0; k < 8; ++k) {
            int i = threadIdx.x + k * 256;
            v[k] = (i >= off) ? sh[i - off] : (T)0;
        }
        __syncthreads();
        for (int k = 0; k < 8; ++k) sh[threadIdx.x + k * 256] += v[k];
        __syncthreads();
    }
    if (totalOut && blockIdx.x == 0 && threadIdx.x == 0)
        *totalOut = (nb > 0) ? sh[nb - 1] : (T)0;
    T add = (blockIdx.x == 0) ? (T)0 : sh[blockIdx.x - 1];
    int base = blockIdx.x * SCAN_TILE;
    int end = base + SCAN_TILE; if (end > n) end = n;
    for (int i = base + threadIdx.x; i < end; i += SCAN_BLOCK) out[i] += add;
}

// Dual scanA: one dispatch covers BOTH independent post-classify scans
// (tetPack u64 over T in blocks [0,nbT); blockHist u32 over nHist in blocks
// [nbT, nbT+nbH)). Saves a dispatch boundary.
__global__ void k_scanA_dual(const u64* in64, u64* out64, int n64, u64* bs64,
                             const u32* in32, u32* out32, int n32, u32* bs32,
                             int nbT) {
    __shared__ u64 tsum[SCAN_BLOCK];
    if ((int)blockIdx.x < nbT) {
        int tbase = blockIdx.x * SCAN_TILE + threadIdx.x * SCAN_ELEMS;
        u64 vals[SCAN_ELEMS]; u64 run = 0;
        for (int k = 0; k < SCAN_ELEMS; ++k) {
            int i = tbase + k;
            u64 v = (i < n64) ? in64[i] : 0ull;
            vals[k] = run; run += v;
        }
        tsum[threadIdx.x] = run;
        __syncthreads();
        for (int off = 1; off < SCAN_BLOCK; off <<= 1) {
            u64 v = (threadIdx.x >= (unsigned)off) ? tsum[threadIdx.x - off] : 0ull;
            __syncthreads();
            tsum[threadIdx.x] += v;
            __syncthreads();
        }
        u64 texcl = (threadIdx.x == 0) ? 0ull : tsum[threadIdx.x - 1];
        for (int k = 0; k < SCAN_ELEMS; ++k) {
            int i = tbase + k;
            if (i < n64) out64[i] = texcl + vals[k];
        }
        if (threadIdx.x == SCAN_BLOCK - 1) bs64[blockIdx.x] = tsum[SCAN_BLOCK - 1];
    } else {
        int blk = (int)blockIdx.x - nbT;
        int tbase = blk * SCAN_TILE + threadIdx.x * SCAN_ELEMS;
        u32 vals[SCAN_ELEMS]; u32 run = 0;
        for (int k = 0; k < SCAN_ELEMS; ++k) {
            int i = tbase + k;
            u32 v = (i < n32) ? in32[i] : 0u;
            vals[k] = run; run += v;
        }
        tsum[threadIdx.x] = (u64)run;
        __syncthreads();
        for (int off = 1; off < SCAN_BLOCK; off <<= 1) {
            u64 v = (threadIdx.x >= (unsigned)off) ? tsum[threadIdx.x - off] : 0ull;
            __syncthreads();
            tsum[threadIdx.x] += v;
            __syncthreads();
        }
        u32 texcl = (threadIdx.x == 0) ? 0u : (u32)tsum[threadIdx.x - 1];
        for (int k = 0; k < SCAN_ELEMS; ++k) {
            int i = tbase + k;
            if (i < n32) out32[i] = texcl + vals[k];
        }
        if (threadIdx.x == SCAN_BLOCK - 1) bs32[blk] = (u32)tsum[SCAN_BLOCK - 1];
    }
}

// Dual scanCf: same block-range split for the fixup passes.
__global__ void k_scanCf_dual(u64* out64, int n64, const u64* bs64, int nb64,
                              u64* total64,
                              u32* out32, int n32, const u32* bs32, int nb32,
                              u32* total32, int nbT) {
    __shared__ u64 sh[2048];        // 16KB
    if ((int)blockIdx.x < nbT) {
        for (int i = threadIdx.x; i < 2048; i += 256)
            sh[i] = (i < nb64) ? bs64[i] : 0ull;
        __syncthreads();
        for (int off = 1; off < 2048; off <<= 1) {
            u64 v[8];
            for (int k = 0; k < 8; ++k) {
                int i = threadIdx.x + k * 256;
                v[k] = (i >= off) ? sh[i - off] : 0ull;
            }
            __syncthreads();
            for (int k = 0; k < 8; ++k) sh[threadIdx.x + k * 256] += v[k];
            __syncthreads();
        }
        if (total64 && blockIdx.x == 0 && threadIdx.x == 0)
            *total64 = (nb64 > 0) ? sh[nb64 - 1] : 0ull;
        u64 add = (blockIdx.x == 0) ? 0ull : sh[blockIdx.x - 1];
        int base = blockIdx.x * SCAN_TILE;
        int end = base + SCAN_TILE; if (end > n64) end = n64;
        for (int i = base + threadIdx.x; i < end; i += SCAN_BLOCK) out64[i] += add;
    } else {
        int blk = (int)blockIdx.x - nbT;
        for (int i = threadIdx.x; i < 2048; i += 256)
            sh[i] = (i < nb32) ? (u64)bs32[i] : 0ull;
        __syncthreads();
        for (int off = 1; off < 2048; off <<= 1) {
            u64 v[8];
            for (int k = 0; k < 8; ++k) {
                int i = threadIdx.x + k * 256;
                v[k] = (i >= off) ? sh[i - off] : 0ull;
            }
            __syncthreads();
            for (int k = 0; k < 8; ++k) sh[threadIdx.x + k * 256] += v[k];
            __syncthreads();
        }
        if (total32 && blk == 0 && threadIdx.x == 0)
            *total32 = (nb32 > 0) ? (u32)sh[nb32 - 1] : 0u;
        u32 add = (blk == 0) ? 0u : (u32)sh[blk - 1];
        int base = blk * SCAN_TILE;
        int end = base + SCAN_TILE; if (end > n32) end = n32;
        for (int i = base + threadIdx.x; i < end; i += SCAN_BLOCK) out32[i] += add;
    }
}

// ---------------- pipeline ----------------
// Pass A: classify tets + per-block LDS histogram of crossing edges over
// bins (binned structure is load-bearing: R6's direct global scatter = 64B
// write-allocate per 8B record = 285us). Zeroes bigCnt.
__global__ __launch_bounds__(256) void k_classify_hist(
    const int* tet, const float* sdf, u8* ti8, u64* tetPack,
    u32* blockHist, u32* bigCnt, int T, int NB, int gB) {
    if (blockIdx.x == 0 && threadIdx.x == 0) *bigCnt = 0;
    __shared__ u32 hist[BIN_VR];
    for (int i = threadIdx.x; i < NB; i += 256) hist[i] = 0;
    __syncthreads();
    int base = blockIdx.x * TETS_PER_BLOCK;
    for (int it = 0; it < TETS_PER_BLOCK / 256; ++it) {
        int t = base + it * 256 + threadIdx.x;
        if (t < T) {
            int4 q = reinterpret_cast<const int4*>(tet)[t];
            int ti = (sdf[q.x] > 0.0f ? 1 : 0) | (sdf[q.y] > 0.0f ? 2 : 0) |
                     (sdf[q.z] > 0.0f ? 4 : 0) | (sdf[q.w] > 0.0f ? 8 : 0);
            ti8[t] = (u8)ti;
            int nt = d_NUMTRI[ti];
            tetPack[t] = ((u64)(nt == 1 ? 1 : 0) << 21) | (u64)(nt == 2 ? 1 : 0);
            if (nt != 0) {
                int idx[4] = {q.x, q.y, q.z, q.w};
                #pragma unroll
                for (int e = 0; e < 6; ++e) {
                    int e0 = d_E0[e], e1 = d_E1[e];
                    if (((ti >> e0) ^ (ti >> e1)) & 1) {
                        int a = idx[e0], b = idx[e1];
                        int mn = a < b ? a : b;
                        atomicAdd(&hist[mn >> BIN_SHIFT], 1u);
                    }
                }
            }
        }
    }
    __syncthreads();
    for (int i = threadIdx.x; i < NB; i += 256)
        blockHist[(size_t)i * gB + blockIdx.x] = hist[i];
}

// Pass B: block-local LDS cursors hand out contiguous slots in the
// bin-sorted record array. ONE u64 record = prov<<32 | ((mn&511)<<18 | mx).
__global__ __launch_bounds__(256) void k_binfill(
    const int* tet, const u8* ti8, const u32* blockHistScan,
    u64* binRec, int T, int NB, int gB) {
    __shared__ u32 cur[BIN_VR];
    for (int i = threadIdx.x; i < NB; i += 256)
        cur[i] = blockHistScan[(size_t)i * gB + blockIdx.x];
    __syncthreads();
    int base = blockIdx.x * TETS_PER_BLOCK;
    for (int it = 0; it < TETS_PER_BLOCK / 256; ++it) {
        int t = base + it * 256 + threadIdx.x;
        if (t < T) {
            int ti = ti8[t];
            if (d_NUMTRI[ti] != 0) {
                int4 q = reinterpret_cast<const int4*>(tet)[t];
                int idx[4] = {q.x, q.y, q.z, q.w};
                #pragma unroll
                for (int e = 0; e < 6; ++e) {
                    int e0 = d_E0[e], e1 = d_E1[e];
                    if (((ti >> e0) ^ (ti >> e1)) & 1) {
                        int a = idx[e0], b = idx[e1];
                        int mn = a < b ? a : b;
                        int mx = a < b ? b : a;
                        u32 slot = atomicAdd(&cur[mn >> BIN_SHIFT], 1u);
                        u32 rec = ((u32)(mn & (BIN_VR - 1)) << 18) | (u32)mx;
                        u32 pv = 6u * (u32)t + (u32)e;
                        binRec[slot] = ((u64)pv << 32) | (u64)rec;
                    }
                }
            }
        }
    }
}

// MERGED bincount+binscatter (R12): one block per bin. The pad4 padding was
// dead (it served k_faces' deleted uint4 scan), and WITHOUT padding the
// bin's bucket windows sum exactly to the bin's record count — so the bin
// base is simply s = blockHistScan[bin*gB], already known. No binTotals, no
// cross-bin scan, no second dispatch, no second 24MB HBM stream (the
// scatter re-read of the bin's ~62KB slice is L2-hot from the hist pass).
__global__ __launch_bounds__(256) void k_binsort(
    const u32* blockHistScan, const u32* totalPtr, const u64* binRec,
    u32* bucketCnt, u32* bucketStart, uint2* rec2, int V, int NB, int gB) {
    int bin = blockIdx.x;
    __shared__ u32 hist[BIN_VR];
    __shared__ u32 sc[BIN_VR];
    __shared__ u32 cur[BIN_VR];
    for (int i = threadIdx.x; i < BIN_VR; i += 256) hist[i] = 0;
    __syncthreads();
    u32 s = blockHistScan[(size_t)bin * gB];
    u32 e = (bin + 1 < NB) ? blockHistScan[(size_t)(bin + 1) * gB] : *totalPtr;
    for (u32 i = s + threadIdx.x; i < e; i += 256)
        atomicAdd(&hist[((u32)binRec[i]) >> 18], 1u);
    __syncthreads();
    int t0 = threadIdx.x, t1 = threadIdx.x + 256;
    sc[t0] = hist[t0];                       // RAW counts (no pad)
    sc[t1] = hist[t1];
    __syncthreads();
    for (int off = 1; off < BIN_VR; off <<= 1) {
        u32 v0 = (t0 >= off) ? sc[t0 - off] : 0u;
        u32 v1 = (t1 >= off) ? sc[t1 - off] : 0u;
        __syncthreads();
        sc[t0] += v0; sc[t1] += v1;          // inclusive scan
        __syncthreads();
    }
    int vbase = bin << BIN_SHIFT;
    for (int i = threadIdx.x; i < BIN_VR; i += 256) {
        int v = vbase + i;
        u32 h = hist[i];
        u32 abs0 = s + sc[i] - h;            // absolute exclusive offset
        if (v < V) {
            bucketCnt[v] = h;
            bucketStart[v] = abs0;
        }
        cur[i] = abs0;
    }
    __syncthreads();
    for (u32 i = s + threadIdx.x; i < e; i += 256) {
        u64 r = binRec[i];                   // L2-hot re-read
        u32 rec = (u32)r;
        u32 pv = (u32)(r >> 32);
        u32 slot = atomicAdd(&cur[rec >> 18], 1u);
        rec2[slot] = make_uint2(rec & 0x3FFFFu, pv);
    }
}

// HOT sort+dedup — R2/R7 measured-best structure: ONE bucket per 64-lane
// wave (wave-UNIFORM n -> SGPR loop), 4 buckets/256-block, zero LDS, no
// barriers. u8 idxmap (dedup idx < 256); plain stores (NT = R3 disaster).
__global__ __launch_bounds__(256) void k_sortdedup(
    const u32* bucketCnt, const u32* bucketStart, uint2* rec2,
    u8* idxmap, u32* crossCnt, u32* bigList, u32* bigCnt, int V)
{
    int v = blockIdx.x * 4 + (threadIdx.x >> 6);
    if (v >= V) return;
    int lane = threadIdx.x & 63;
    int n = (int)bucketCnt[v];
    if (n == 0) { if (lane == 0) crossCnt[v] = 0; return; }
    if (n > 64) {
        if (lane == 0) bigList[atomicAdd(bigCnt, 1u)] = (u32)v;
        return;
    }
    long long start = (long long)bucketStart[v];
    uint2 rp = (lane < n) ? rec2[start + lane] : make_uint2(0xFFFFFFFFu, 0u);
    u32 key = rp.x, prov = rp.y;
    int rank = 0;
    for (int j = 0; j < n; ++j) {               // wave-uniform bound, avg ~15
        u32 kj = (u32)__shfl((int)key, j);
        rank += (kj < key || (kj == key && j < lane)) ? 1 : 0;
    }
    u32 sorted = (u32)__builtin_amdgcn_ds_permute(rank << 2, (int)key);
    u32 prev = (u32)__shfl((int)sorted, lane - 1);
    bool nf = (lane < n) && (lane == 0 || prev != sorted);
    u64 m = __ballot(nf);
    int idx = __popcll(m & ((1ull << lane) - 1ull));
    if (nf) rec2[start + idx].x = sorted;
    int ldSorted = nf ? idx : idx - 1;          // dedup idx at sorted pos lane
    int ldOrig = __shfl(ldSorted, rank);        // my record sits at pos rank
    if (lane < n) idxmap[prov] = (u8)ldOrig;
    if (lane == 0) crossCnt[v] = (u32)__popcll(m);
}

// Overflow (64<n<=256, rare low-index buckets): full wave per bucket,
// register-chunked (4x64) two-pass shfl rank/dedup — no LDS, no serial work
// (R4 lesson: lane-0 insertion sort on real buckets = 207us tail). Serial
// remains only for n>256 (needs a vertex in ~85+ tets; P~0).
__global__ __launch_bounds__(256) void k_sortbig(
    const u32* bigList, const u32* bigCnt, const u32* bucketCnt,
    const u32* bucketStart, uint2* rec2, u8* idxmap, u32* crossCnt)
{
    int nbig = (int)*bigCnt;
    int lane = threadIdx.x & 63;
    int wave = (blockIdx.x << 2) + (threadIdx.x >> 6);
    int stride = gridDim.x << 2;
    for (int b = wave; b < nbig; b += stride) {
        int v = (int)bigList[b];
        int n = (int)bucketCnt[v];
        long long start = (long long)bucketStart[v];
        if (n <= 256) {
            int chunks = (n + 63) >> 6;         // 1..4
            u32 key[4], prov[4], kf[4];
            int myi[4];
            #pragma unroll
            for (int c = 0; c < 4; ++c) {
                myi[c] = (c << 6) + lane;
                key[c] = 0xFFFFFFFFu; prov[c] = 0u;
                if (c < chunks && myi[c] < n) {
                    uint2 rp = rec2[start + myi[c]];
                    key[c] = rp.x; prov[c] = rp.y;
                }
            }
            bool tie[4] = {false, false, false, false};
            #pragma unroll
            for (int c2 = 0; c2 < 4; ++c2) {
                if (c2 < chunks) {
                    int base2 = c2 << 6;
                    int lim = n - base2; if (lim > 64) lim = 64;
                    for (int j = 0; j < lim; ++j) {
                        u32 kj = (u32)__shfl((int)key[c2], j);
                        int jg = base2 + j;
                        #pragma unroll
                        for (int c = 0; c < 4; ++c) {
                            if (c < chunks)
                                tie[c] = tie[c] | (kj == key[c] && jg < myi[c]);
                        }
                    }
                }
            }
            u32 uq = 0;
            #pragma unroll
            for (int c = 0; c < 4; ++c) {
                bool isf = (c < chunks) && (myi[c] < n) && !tie[c];
                kf[c] = key[c] | (isf ? 0x80000000u : 0u);
                u64 bal = __ballot(isf);
                uq += (u32)__popcll(bal);
            }
            int uless[4] = {0, 0, 0, 0};
            #pragma unroll
            for (int c2 = 0; c2 < 4; ++c2) {
                if (c2 < chunks) {
                    int base2 = c2 << 6;
                    int lim = n - base2; if (lim > 64) lim = 64;
                    for (int j = 0; j < lim; ++j) {
                        u32 kfj = (u32)__shfl((int)kf[c2], j);
                        u32 kj = kfj & 0x7FFFFFFFu;
                        bool fj = (kfj & 0x80000000u) != 0u;
                        #pragma unroll
                        for (int c = 0; c < 4; ++c) {
                            if (c < chunks)
                                uless[c] += (fj && kj < key[c]) ? 1 : 0;
                        }
                    }
                }
            }
            #pragma unroll
            for (int c = 0; c < 4; ++c) {
                if (c < chunks && myi[c] < n) {
                    if (kf[c] & 0x80000000u)
                        rec2[start + uless[c]].x = key[c];
                    idxmap[prov[c]] = (u8)uless[c];
                }
            }
            if (lane == 0) crossCnt[v] = uq;
        } else if (lane == 0) {
            for (int i = 1; i < n; ++i) {
                uint2 kk = rec2[start + i];
                int j = i - 1;
                while (j >= 0 && rec2[start + j].x > kk.x) {
                    rec2[start + j + 1] = rec2[start + j]; --j;
                }
                rec2[start + j + 1] = kk;
            }
            int uc = 0; u32 prev = 0xFFFFFFFFu;
            for (int i = 0; i < n; ++i) {
                uint2 r = rec2[start + i];
                if (r.x != prev) { rec2[start + uc].x = r.x; ++uc; prev = r.x; }
                idxmap[r.y] = (u8)(uc - 1);
            }
            crossCnt[v] = (u32)uc;
        }
    }
}

// 32-lane segments, 8 buckets per 256-block; lane i -> unique crossing edge
// i -> vertex crossScan[v]+i. Strided loop handles u>32.
__global__ __launch_bounds__(256) void k_verts(
    const u32* crossCnt, const u32* bucketStart, const uint2* rec2, const u32* crossScan,
    const float* pos, const float* sdf, float* out, int V)
{
    int v = blockIdx.x * 8 + (threadIdx.x >> 5);
    if (v >= V) return;
    int slane = threadIdx.x & 31;
    int u = (int)crossCnt[v];
    if (u == 0) return;
    long long start = (long long)bucketStart[v];
    int cBase = (int)crossScan[v];
    float s0 = sdf[v];
    float p0x = pos[3 * v], p0y = pos[3 * v + 1], p0z = pos[3 * v + 2];
    for (int i = slane; i < u; i += 32) {
        int b = (int)rec2[start + i].x;
        long long k = cBase + i;
        float s1 = sdf[b];
        float d = s0 - s1;
        float w0 = -s1 / d, w1 = s0 / d;
        out[3 * k + 0] = p0x * w0 + pos[3 * b + 0] * w1;
        out[3 * k + 1] = p0y * w0 + pos[3 * b + 1] * w1;
        out[3 * k + 2] = p0z * w0 + pos[3 * b + 2] * w1;
    }
}

// faces + uv_idx + fused uv grid (Ngrid^2 >= T since M == T). Edge->vertex
// id: u8 idx_map[6t+e] = local dedup index; global id = crossScan[a]+local.
__global__ void k_faces(const int* tet, const u8* ti8, const u64* tetScan,
                        const u8* idxmap, const u32* crossScan,
                        const u64* meta0, const u32* NePtr,
                        float* out, int T, int Ngrid, long long uvFloats)
{
    int t = blockIdx.x * 256 + threadIdx.x;
    int uvTotal = Ngrid * Ngrid;
    if (t >= T && t >= uvTotal) return;

    u64 tot = *meta0;
    int C1 = (int)((tot >> 21) & 0x1fffffull);
    int C2 = (int)(tot & 0x1fffffull);
    int Ne = (int)*NePtr;
    long long facesBase = 3LL * Ne;
    long long F = (long long)C1 + 2LL * C2;
    long long uvBase = facesBase + 3LL * F;
    long long uvIdxBase = uvBase + uvFloats;

    if (t < uvTotal) {          // fused uv-grid write
        int i = t / Ngrid, j = t % Ngrid;
        double step = (Ngrid > 1) ? (1.0 - 1.0 / (double)Ngrid) / (double)(Ngrid - 1) : 0.0;
        float x = (float)((double)j * step);
        float y = (float)((double)i * step);
        float pad = (float)(0.9 / (double)Ngrid);
        long long o = uvBase + 8LL * t;
        out[o + 0] = x;       out[o + 1] = y;
        out[o + 2] = x + pad; out[o + 3] = y;
        out[o + 4] = x + pad; out[o + 5] = y + pad;
        out[o + 6] = x;       out[o + 7] = y + pad;
    }
    if (t >= T) return;

    int ti = ti8[t];
    int nt = d_NUMTRI[ti];
    if (nt == 0) return;

    int4 q = reinterpret_cast<const int4*>(tet)[t];
    int idx[4] = {q.x, q.y, q.z, q.w};
    const unsigned short* imp =
        reinterpret_cast<const unsigned short*>(idxmap + 6ll * t);
    unsigned short w0 = imp[0], w1 = imp[1], w2 = imp[2];
    u32 im[6] = {(u32)(w0 & 0xFF), (u32)(w0 >> 8),
                 (u32)(w1 & 0xFF), (u32)(w1 >> 8),
                 (u32)(w2 & 0xFF), (u32)(w2 >> 8)};
    const int* row = d_TRI[ti];

    int emap[6];
    unsigned done = 0;
    float fv[6];
    #pragma unroll
    for (int j = 0; j < 6; ++j) {
        if (j >= 3 * nt) break;
        int e = row[j];
        if (!((done >> e) & 1)) {
            done |= 1u << e;
            int a = idx[d_E0[e]], b = idx[d_E1[e]];
            if (b < a) a = b;                  // a = min endpoint = bucket
            emap[e] = (int)crossScan[a] + (int)im[e];
        }
        fv[j] = (float)emap[e];
    }

    u64 sc = tetScan[t];
    int r1s = (int)((sc >> 21) & 0x1fffffull);
    int r2s = (int)(sc & 0x1fffffull);
    int tet_idx = (t / Ngrid) * Ngrid + (t % Ngrid);

    if (nt == 1) {
        long long f = r1s;
        out[facesBase + 3 * f + 0] = fv[0];
        out[facesBase + 3 * f + 1] = fv[1];
        out[facesBase + 3 * f + 2] = fv[2];
        out[uvIdxBase + 3 * f + 0] = (float)(4 * tet_idx);
        out[uvIdxBase + 3 * f + 1] = (float)(4 * tet_idx + 1);
        out[uvIdxBase + 3 * f + 2] = (float)(4 * tet_idx + 2);
    } else {
        long long f0 = (long long)C1 + 2LL * r2s;
        out[facesBase + 3 * f0 + 0] = fv[0];
        out[facesBase + 3 * f0 + 1] = fv[1];
        out[facesBase + 3 * f0 + 2] = fv[2];
        out[facesBase + 3 * (f0 + 1) + 0] = fv[3];
        out[facesBase + 3 * (f0 + 1) + 1] = fv[4];
        out[facesBase + 3 * (f0 + 1) + 2] = fv[5];
        out[uvIdxBase + 3 * f0 + 0] = (float)(4 * tet_idx);
        out[uvIdxBase + 3 * f0 + 1] = (float)(4 * tet_idx + 1);
        out[uvIdxBase + 3 * f0 + 2] = (float)(4 * tet_idx + 2);
        out[uvIdxBase + 3 * (f0 + 1) + 0] = (float)(4 * tet_idx);
        out[uvIdxBase + 3 * (f0 + 1) + 1] = (float)(4 * tet_idx + 2);
        out[uvIdxBase + 3 * (f0 + 1) + 2] = (float)(4 * tet_idx + 3);
    }
}

// ---------------- host ----------------
template <typename T>
static void run_scan2(const T* in, T* out, int n, T* blockSums, T* totalOut,
                      hipStream_t stream) {
    int nb = (n + SCAN_TILE - 1) / SCAN_TILE;
    scanA_t<T><<<nb, SCAN_BLOCK, 0, stream>>>(in, out, n, blockSums);
    scanCf_t<T><<<nb, SCAN_BLOCK, 0, stream>>>(out, n, blockSums, nb, totalOut);
}

extern "C" void kernel_launch(void* const* d_in, const int* in_sizes, int n_in,
                              void* d_out, int out_size, void* d_ws, size_t ws_size,
                              hipStream_t stream) {
    const float* pos = (const float*)d_in[0];
    const float* sdf = (const float*)d_in[1];
    const int* tet = (const int*)d_in[2];
    int V = in_sizes[1];
    int T = in_sizes[2] / 4;
    float* out = (float*)d_out;

    int NB = (V + BIN_VR - 1) / BIN_VR;
    int gB = (T + TETS_PER_BLOCK - 1) / TETS_PER_BLOCK;
    int nHist = NB * gB;

    char* p = (char*)d_ws;
    auto alloc = [&](size_t bytes) -> void* {
        void* r = (void*)p;
        p += (bytes + 255) & ~(size_t)255;
        return r;
    };
    u8*  ti8           = (u8*) alloc((size_t)T);
    u64* tetPack       = (u64*)alloc((size_t)T * 8);
    u64* tetScan       = (u64*)alloc((size_t)T * 8);
    u32* blockHist     = (u32*)alloc((size_t)nHist * 4);
    u32* blockHistScan = (u32*)alloc((size_t)nHist * 4);
    u64* binRec        = (u64*)alloc((size_t)6 * T * 8);   // reused as idxmap
    u32* bucketCnt     = (u32*)alloc((size_t)V * 4);
    u32* bucketStart   = (u32*)alloc((size_t)V * 4);
    u32* crossCnt      = (u32*)alloc((size_t)V * 4);
    u32* crossScan     = (u32*)alloc((size_t)V * 4);
    uint2* rec2        = (uint2*)alloc(((size_t)6 * T + 4 * (size_t)V) * 8);
    u32* bigList       = (u32*)alloc((size_t)V * 4);
    u64* blockSums64   = (u64*)alloc(2048 * 8);
    u32* blockSums32   = (u32*)alloc(2048 * 4);
    u64* meta64        = (u64*)alloc(8 * 8);
    u32* NePtr         = (u32*)(meta64 + 4);
    u32* NeInstPtr     = (u32*)(meta64 + 5);
    u32* bigCnt        = (u32*)(meta64 + 6);

    // u8 idxmap (6T bytes) aliases binRec (48T bytes): binRec's last reader
    // is k_binsort, idxmap's first writer is k_sortdedup.
    u8* idxmap = (u8*)binRec;

    long long M = (2LL * T + 1) / 2;
    int Ngrid = (int)std::sqrt((double)M);
    while ((long long)Ngrid * Ngrid < M) ++Ngrid;
    if (Ngrid < 1) Ngrid = 1;
    long long uvFloats = 8LL * Ngrid * Ngrid;

    int gV4 = (V + 3) / 4;
    int gV8 = (V + 7) / 8;
    long long fw = (long long)Ngrid * Ngrid;          // >= T (M == T)
    if (fw < (long long)T) fw = T;
    int gFU = (int)((fw + 255) / 256);

    int nbT = (T + SCAN_TILE - 1) / SCAN_TILE;
    int nbH = (nHist + SCAN_TILE - 1) / SCAN_TILE;

    k_classify_hist<<<gB, 256, 0, stream>>>(tet, sdf, ti8, tetPack, blockHist,
                                            bigCnt, T, NB, gB);
    // fused dual scan: tetPack (u64, T) + blockHist (u32, nHist)
    k_scanA_dual<<<nbT + nbH, SCAN_BLOCK, 0, stream>>>(
        tetPack, tetScan, T, blockSums64,
        blockHist, blockHistScan, nHist, blockSums32, nbT);
    k_scanCf_dual<<<nbT + nbH, SCAN_BLOCK, 0, stream>>>(
        tetScan, T, blockSums64, nbT, meta64,
        blockHistScan, nHist, blockSums32, nbH, NeInstPtr, nbT);
    k_binfill<<<gB, 256, 0, stream>>>(tet, ti8, blockHistScan, binRec,
                                      T, NB, gB);
    k_binsort<<<NB, 256, 0, stream>>>(blockHistScan, NeInstPtr, binRec,
                                      bucketCnt, bucketStart, rec2, V, NB, gB);
    k_sortdedup<<<gV4, 256, 0, stream>>>(bucketCnt, bucketStart, rec2,
                                         idxmap, crossCnt, bigList, bigCnt, V);
    k_sortbig<<<1024, 256, 0, stream>>>(bigList, bigCnt, bucketCnt, bucketStart,
                                        rec2, idxmap, crossCnt);
    run_scan2<u32>(crossCnt, crossScan, V, blockSums32, NePtr, stream);
    k_verts<<<gV8, 256, 0, stream>>>(crossCnt, bucketStart, rec2, crossScan,
                                     pos, sdf, out, V);
    k_faces<<<gFU, 256, 0, stream>>>(tet, ti8, tetScan, idxmap, crossScan,
                                     meta64, NePtr, out, T, Ngrid, uvFloats);
}